// Round 1
// baseline (11366.856 us; speedup 1.0000x reference)
//
#include <hip/hip_runtime.h>
#include <cmath>

#define DD 64

namespace {

constexpr int U_N = 50000, B_N = 20000, I_N = 100000;
constexpr int BATCH = 2048;

__device__ __forceinline__ float wave_sum(float v) {
#pragma unroll
  for (int off = 32; off > 0; off >>= 1) v += __shfl_xor(v, off);
  return v;
}

__device__ __forceinline__ void atomAddF(float* p, float v) {
  unsafeAtomicAdd(p, v);  // native global_atomic_add_f32, no CAS loop
}

// cur = concat(A, Bf); out = cur * (1/3)   (layer-0 term, unnormalized)
__global__ void k_init(const float* __restrict__ A, const float* __restrict__ Bf,
                       float* __restrict__ cur, float* __restrict__ out,
                       int nA, int nTot) {
  int idx = blockIdx.x * 256 + threadIdx.x;
  int tot4 = nTot * (DD / 4);
  if (idx >= tot4) return;
  int nA4 = nA * (DD / 4);
  float4 v = (idx < nA4) ? ((const float4*)A)[idx] : ((const float4*)Bf)[idx - nA4];
  ((float4*)cur)[idx] = v;
  float4 o;
  o.x = v.x * (1.f / 3.f); o.y = v.y * (1.f / 3.f);
  o.z = v.z * (1.f / 3.f); o.w = v.w * (1.f / 3.f);
  ((float4*)out)[idx] = o;
}

// out[rows[e]] += vals[e] * x[cols[e]]   (16 lanes of float4 per edge)
__global__ void k_spmm(const int* __restrict__ rows, const int* __restrict__ cols,
                       const float* __restrict__ vals, const float* __restrict__ x,
                       float* __restrict__ out, int nnz) {
  long long t = (long long)blockIdx.x * 256 + threadIdx.x;
  int e = (int)(t >> 4);
  if (e >= nnz) return;
  int l = (int)(t & 15);
  int c = cols[e];
  int r = rows[e];
  float v = vals[e];
  float4 xv = ((const float4*)(x + (size_t)c * DD))[l];
  float* o = out + (size_t)r * DD + (size_t)l * 4;
  atomAddF(o + 0, v * xv.x);
  atomAddF(o + 1, v * xv.y);
  atomAddF(o + 2, v * xv.z);
  atomAddF(o + 3, v * xv.w);
}

// f = g + sign(g)*l2norm(noise_row)*0.1 (in place); out += l2norm(f)/3
__global__ void k_post_prop(float* __restrict__ f, const float* __restrict__ noise,
                            float* __restrict__ out, int n) {
  long long t = (long long)blockIdx.x * 256 + threadIdx.x;
  int row = (int)(t >> 6);
  int lane = (int)(t & 63);
  if (row >= n) return;
  size_t base = (size_t)row * DD + lane;
  float g = f[base];
  float nz = noise[base];
  float nn = wave_sum(nz * nz);
  float nf = 0.1f / fmaxf(sqrtf(nn), 1e-12f);
  float s = (g > 0.f) ? 1.f : ((g < 0.f) ? -1.f : 0.f);
  float fv = g + s * nz * nf;
  f[base] = fv;
  float fn = wave_sum(fv * fv);
  float inv = (1.f / 3.f) / fmaxf(sqrtf(fn), 1e-12f);
  out[base] += fv * inv;
}

// agg = agg + sign(agg)*l2norm(noise_row)*0.1  (in place)
__global__ void k_post_agg(float* __restrict__ agg, const float* __restrict__ noise, int n) {
  long long t = (long long)blockIdx.x * 256 + threadIdx.x;
  int row = (int)(t >> 6);
  int lane = (int)(t & 63);
  if (row >= n) return;
  size_t base = (size_t)row * DD + lane;
  float g = agg[base];
  float nz = noise[base];
  float nn = wave_sum(nz * nz);
  float nf = 0.1f / fmaxf(sqrtf(nn), 1e-12f);
  float s = (g > 0.f) ? 1.f : ((g < 0.f) ? -1.f : 0.f);
  agg[base] = g + s * nz * nf;
}

// one wave per batch element: softplus(neg-pos) summed into accs[0]
__global__ void k_bpr(const float* __restrict__ o_UI, const float* __restrict__ biu,
                      const float* __restrict__ uib, const float* __restrict__ o_BI,
                      const int* __restrict__ users, const int* __restrict__ bundles,
                      float* __restrict__ accs) {
  long long t = (long long)blockIdx.x * 256 + threadIdx.x;
  int w = (int)(t >> 6);
  int lane = (int)(t & 63);
  if (w >= BATCH) return;
  int u = users[w];
  int b0 = bundles[2 * w], b1 = bundles[2 * w + 1];
  float ur = 0.5f * (o_UI[(size_t)u * DD + lane] + biu[(size_t)u * DD + lane]);
  float br0 = 0.5f * (uib[(size_t)b0 * DD + lane] + o_BI[(size_t)b0 * DD + lane]);
  float br1 = 0.5f * (uib[(size_t)b1 * DD + lane] + o_BI[(size_t)b1 * DD + lane]);
  float pos = wave_sum(ur * br0);
  float neg = wave_sum(ur * br1);
  if (lane == 0) {
    float x = pos - neg;
    float loss = (x > 0.f) ? log1pf(expf(-x)) : (-x + log1pf(expf(x)));
    atomAddF(&accs[0], loss);
  }
}

__global__ void k_sumsq(const float* __restrict__ x, int n4, float* __restrict__ acc) {
  float s = 0.f;
  for (int i = blockIdx.x * 256 + threadIdx.x; i < n4; i += gridDim.x * 256) {
    float4 v = ((const float4*)x)[i];
    s += v.x * v.x + v.y * v.y + v.z * v.z + v.w * v.w;
  }
  s = wave_sum(s);
  __shared__ float part[4];
  if ((threadIdx.x & 63) == 0) part[threadIdx.x >> 6] = s;
  __syncthreads();
  if (threadIdx.x == 0) atomAddF(acc, part[0] + part[1] + part[2] + part[3]);
}

// build 6 normalized (2048 x 64) matrices for the CL losses
__global__ void k_gather(const float* __restrict__ o_UB, const float* __restrict__ o_UI,
                         const float* __restrict__ o_BI, const float* __restrict__ uib,
                         const float* __restrict__ biu, const int* __restrict__ users,
                         const int* __restrict__ bundles, float* __restrict__ P) {
  long long t = (long long)blockIdx.x * 256 + threadIdx.x;
  int w = (int)(t >> 6);
  int lane = (int)(t & 63);
  if (w >= 6 * BATCH) return;
  int k = w / BATCH, b = w % BATCH;
  const float* src;
  if (k == 0)      src = o_UB + (size_t)users[b] * DD;                  // UB_u[u0]
  else if (k == 1) src = o_UI + (size_t)users[b] * DD;                  // UI_u[u0]
  else if (k == 2) src = biu + (size_t)users[b] * DD;                   // BI_u[u0]
  else if (k == 3) src = o_UB + (size_t)(U_N + bundles[2 * b]) * DD;    // UB_b[b0]
  else if (k == 4) src = uib + (size_t)bundles[2 * b] * DD;             // UI_b[b0]
  else             src = o_BI + (size_t)bundles[2 * b] * DD;            // BI_b[b0]
  float v = src[lane];
  float n2 = wave_sum(v * v);
  float inv = 1.f / fmaxf(sqrtf(n2), 1e-12f);
  P[(size_t)w * DD + lane] = v * inv;
}

// per (pair, 64-row i-tile): ttl_i = sum_j exp(X_i . Y_j * 4)
__global__ void k_clpair(const float* __restrict__ P, float* __restrict__ ttl) {
  __shared__ float Xs[64][65];
  __shared__ float Ys[64][65];
  const int pairX[12] = {0, 0, 1, 0, 1, 2, 3, 3, 4, 3, 4, 5};
  const int pairY[12] = {1, 2, 2, 0, 1, 2, 4, 5, 5, 3, 4, 5};
  int p = blockIdx.x >> 5;
  int it = blockIdx.x & 31;
  const float* X = P + (size_t)pairX[p] * BATCH * DD;
  const float* Y = P + (size_t)pairY[p] * BATCH * DD;
  int tx = threadIdx.x;
#pragma unroll
  for (int r = 0; r < 4; ++r) {
    int idx = tx + r * 256;
    int row = idx >> 4, c4 = idx & 15;
    float4 v = ((const float4*)(X + (size_t)(it * 64 + row) * DD))[c4];
    Xs[row][c4 * 4 + 0] = v.x; Xs[row][c4 * 4 + 1] = v.y;
    Xs[row][c4 * 4 + 2] = v.z; Xs[row][c4 * 4 + 3] = v.w;
  }
  int ti = tx & 15, tj = tx >> 4;
  float acc[4] = {0.f, 0.f, 0.f, 0.f};
  for (int jt = 0; jt < 32; ++jt) {
    __syncthreads();
#pragma unroll
    for (int r = 0; r < 4; ++r) {
      int idx = tx + r * 256;
      int row = idx >> 4, c4 = idx & 15;
      float4 v = ((const float4*)(Y + (size_t)(jt * 64 + row) * DD))[c4];
      Ys[row][c4 * 4 + 0] = v.x; Ys[row][c4 * 4 + 1] = v.y;
      Ys[row][c4 * 4 + 2] = v.z; Ys[row][c4 * 4 + 3] = v.w;
    }
    __syncthreads();
    float d[4][4];
#pragma unroll
    for (int ii = 0; ii < 4; ++ii)
#pragma unroll
      for (int jj = 0; jj < 4; ++jj) d[ii][jj] = 0.f;
    for (int k = 0; k < 64; ++k) {
      float a[4], b[4];
#pragma unroll
      for (int ii = 0; ii < 4; ++ii) a[ii] = Xs[ti * 4 + ii][k];
#pragma unroll
      for (int jj = 0; jj < 4; ++jj) b[jj] = Ys[tj * 4 + jj][k];
#pragma unroll
      for (int ii = 0; ii < 4; ++ii)
#pragma unroll
        for (int jj = 0; jj < 4; ++jj) d[ii][jj] = fmaf(a[ii], b[jj], d[ii][jj]);
    }
#pragma unroll
    for (int ii = 0; ii < 4; ++ii)
#pragma unroll
      for (int jj = 0; jj < 4; ++jj) acc[ii] += __expf(d[ii][jj] * 4.0f);
  }
  __syncthreads();
  float* red = &Xs[0][0];
#pragma unroll
  for (int ii = 0; ii < 4; ++ii) red[(ti * 4 + ii) * 17 + tj] = acc[ii];
  __syncthreads();
  if (tx < 64) {
    float s = 0.f;
#pragma unroll
    for (int t2 = 0; t2 < 16; ++t2) s += red[tx * 17 + t2];
    ttl[(size_t)p * BATCH + it * 64 + tx] = s;
  }
}

// per (pair, i): log(ttl) - diag/tau -> inter/intra accumulators
__global__ void k_cldiag(const float* __restrict__ P, const float* __restrict__ ttl,
                         float* __restrict__ accs) {
  const int pairX[12] = {0, 0, 1, 0, 1, 2, 3, 3, 4, 3, 4, 5};
  const int pairY[12] = {1, 2, 2, 0, 1, 2, 4, 5, 5, 3, 4, 5};
  long long t = (long long)blockIdx.x * 256 + threadIdx.x;
  int w = (int)(t >> 6);
  int lane = (int)(t & 63);
  if (w >= 12 * BATCH) return;
  int p = w / BATCH, i = w % BATCH;
  float xv = P[((size_t)pairX[p] * BATCH + i) * DD + lane];
  float yv = P[((size_t)pairY[p] * BATCH + i) * DD + lane];
  float d = wave_sum(xv * yv);
  if (lane == 0) {
    float term = logf(ttl[(size_t)p * BATCH + i]) - d * 4.0f;
    bool inter = (p % 6) < 3;
    atomAddF(&accs[inter ? 2 : 3], term);
  }
}

__global__ void k_final(const float* __restrict__ accs, float* __restrict__ out) {
  if (threadIdx.x == 0 && blockIdx.x == 0) {
    out[0] = accs[0] / (float)BATCH + 1e-5f * accs[1];
    out[1] = 0.04f * (0.5f * accs[2] + 0.5f * accs[3]) / (float)BATCH;
  }
}

}  // namespace

extern "C" void kernel_launch(void* const* d_in, const int* in_sizes, int n_in,
                              void* d_out, int out_size, void* d_ws, size_t ws_size,
                              hipStream_t stream) {
  const float* usersF = (const float*)d_in[0];
  const float* bundlesF = (const float*)d_in[1];
  const float* itemsF = (const float*)d_in[2];
  const int* ub_rows = (const int*)d_in[3];
  const int* ub_cols = (const int*)d_in[4];
  const float* ub_vals = (const float*)d_in[5];
  const int* ui_rows = (const int*)d_in[6];
  const int* ui_cols = (const int*)d_in[7];
  const float* ui_vals = (const float*)d_in[8];
  const int* bi_rows = (const int*)d_in[9];
  const int* bi_cols = (const int*)d_in[10];
  const float* bi_vals = (const float*)d_in[11];
  const int* biagg_rows = (const int*)d_in[12];
  const int* biagg_cols = (const int*)d_in[13];
  const float* biagg_vals = (const float*)d_in[14];
  const int* uiagg_rows = (const int*)d_in[15];
  const int* uiagg_cols = (const int*)d_in[16];
  const float* uiagg_vals = (const float*)d_in[17];
  const float* noise_UB = (const float*)d_in[18];
  const float* noise_UI = (const float*)d_in[19];
  const float* noise_BI = (const float*)d_in[20];
  const float* noise_agg_BI = (const float*)d_in[21];
  const float* noise_agg_UI = (const float*)d_in[22];
  const int* users = (const int*)d_in[23];
  const int* bundles = (const int*)d_in[24];
  int nnz_ub = in_sizes[3], nnz_ui = in_sizes[6], nnz_bi = in_sizes[9];
  int nnz_biagg = in_sizes[12], nnz_uiagg = in_sizes[15];

  float* ws = (float*)d_ws;
  size_t off = 0;
  float* o_UB = ws + off; off += (size_t)(U_N + B_N) * DD;
  float* o_UI = ws + off; off += (size_t)(U_N + I_N) * DD;
  float* o_BI = ws + off; off += (size_t)(B_N + I_N) * DD;
  float* uib  = ws + off; off += (size_t)B_N * DD;
  float* biu  = ws + off; off += (size_t)U_N * DD;
  float* s1   = ws + off; off += (size_t)(U_N + I_N) * DD;
  float* s2   = ws + off; off += (size_t)(U_N + I_N) * DD;
  float* P    = ws + off; off += (size_t)6 * BATCH * DD;
  float* ttl  = ws + off; off += (size_t)12 * BATCH;
  float* accs = ws + off; off += 8;
  if (ws_size < off * sizeof(float)) return;  // insufficient workspace

  hipMemsetAsync(accs, 0, 8 * sizeof(float), stream);

  auto propagate = [&](const float* A, const float* Bf, int nA, int nB,
                       const int* rws, const int* cls, const float* vls, int nnz,
                       const float* noise, float* outp) {
    int n = nA + nB;
    int tot4 = n * (DD / 4);
    k_init<<<(tot4 + 255) / 256, 256, 0, stream>>>(A, Bf, s1, outp, nA, n);
    hipMemsetAsync(s2, 0, (size_t)n * DD * sizeof(float), stream);
    long long th = (long long)nnz * 16;
    int gs = (int)((th + 255) / 256);
    int gp = (int)(((long long)n * 64 + 255) / 256);
    k_spmm<<<gs, 256, 0, stream>>>(rws, cls, vls, s1, s2, nnz);
    k_post_prop<<<gp, 256, 0, stream>>>(s2, noise, outp, n);
    hipMemsetAsync(s1, 0, (size_t)n * DD * sizeof(float), stream);
    k_spmm<<<gs, 256, 0, stream>>>(rws, cls, vls, s2, s1, nnz);
    k_post_prop<<<gp, 256, 0, stream>>>(s1, noise + (size_t)n * DD, outp, n);
  };

  propagate(usersF, bundlesF, U_N, B_N, ub_rows, ub_cols, ub_vals, nnz_ub, noise_UB, o_UB);
  propagate(usersF, itemsF, U_N, I_N, ui_rows, ui_cols, ui_vals, nnz_ui, noise_UI, o_UI);
  propagate(bundlesF, itemsF, B_N, I_N, bi_rows, bi_cols, bi_vals, nnz_bi, noise_BI, o_BI);

  // UI_b = aggregate(biagg, UI_i)
  hipMemsetAsync(uib, 0, (size_t)B_N * DD * sizeof(float), stream);
  k_spmm<<<(int)(((long long)nnz_biagg * 16 + 255) / 256), 256, 0, stream>>>(
      biagg_rows, biagg_cols, biagg_vals, o_UI + (size_t)U_N * DD, uib, nnz_biagg);
  k_post_agg<<<(int)(((long long)B_N * 64 + 255) / 256), 256, 0, stream>>>(
      uib, noise_agg_BI, B_N);

  // BI_u = aggregate(uiagg, BI_i)
  hipMemsetAsync(biu, 0, (size_t)U_N * DD * sizeof(float), stream);
  k_spmm<<<(int)(((long long)nnz_uiagg * 16 + 255) / 256), 256, 0, stream>>>(
      uiagg_rows, uiagg_cols, uiagg_vals, o_BI + (size_t)B_N * DD, biu, nnz_uiagg);
  k_post_agg<<<(int)(((long long)U_N * 64 + 255) / 256), 256, 0, stream>>>(
      biu, noise_agg_UI, U_N);

  // BPR loss
  k_bpr<<<BATCH * 64 / 256, 256, 0, stream>>>(o_UI, biu, uib, o_BI, users, bundles, accs);
  // Regularizer
  k_sumsq<<<1024, 256, 0, stream>>>(usersF, U_N * DD / 4, accs + 1);
  k_sumsq<<<1024, 256, 0, stream>>>(bundlesF, B_N * DD / 4, accs + 1);
  k_sumsq<<<1024, 256, 0, stream>>>(itemsF, I_N * DD / 4, accs + 1);
  // CL losses
  k_gather<<<6 * BATCH * 64 / 256, 256, 0, stream>>>(o_UB, o_UI, o_BI, uib, biu,
                                                     users, bundles, P);
  k_clpair<<<12 * 32, 256, 0, stream>>>(P, ttl);
  k_cldiag<<<12 * BATCH * 64 / 256, 256, 0, stream>>>(P, ttl, accs);
  k_final<<<1, 64, 0, stream>>>(accs, (float*)d_out);
}

// Round 2
// 3143.976 us; speedup vs baseline: 3.6154x; 3.6154x over previous
//
#include <hip/hip_runtime.h>
#include <cmath>

#define DD 64

namespace {

constexpr int U_N = 50000, B_N = 20000, I_N = 100000;
constexpr int BATCH = 2048;
constexpr int MAX_N = U_N + I_N;        // largest row count (150000)
constexpr int MAX_NNZ = 2000000;        // largest edge count (UI doubled)

__device__ __forceinline__ float wave_sum(float v) {
#pragma unroll
  for (int off = 32; off > 0; off >>= 1) v += __shfl_xor(v, off);
  return v;
}

__device__ __forceinline__ void atomAddF(float* p, float v) {
  unsafeAtomicAdd(p, v);  // native global_atomic_add_f32
}

// cur = concat(A, Bf); out = cur * (1/3)   (layer-0 term, unnormalized)
__global__ void k_init(const float* __restrict__ A, const float* __restrict__ Bf,
                       float* __restrict__ cur, float* __restrict__ out,
                       int nA, int nTot) {
  int idx = blockIdx.x * 256 + threadIdx.x;
  int tot4 = nTot * (DD / 4);
  if (idx >= tot4) return;
  int nA4 = nA * (DD / 4);
  float4 v = (idx < nA4) ? ((const float4*)A)[idx] : ((const float4*)Bf)[idx - nA4];
  ((float4*)cur)[idx] = v;
  float4 o;
  o.x = v.x * (1.f / 3.f); o.y = v.y * (1.f / 3.f);
  o.z = v.z * (1.f / 3.f); o.w = v.w * (1.f / 3.f);
  ((float4*)out)[idx] = o;
}

// ---------------- CSR build ----------------

__global__ void k_hist(const int* __restrict__ rows, int nnz, int* __restrict__ cnt) {
  int e = blockIdx.x * 256 + threadIdx.x;
  if (e < nnz) atomicAdd(&cnt[rows[e]], 1);
}

// single-workgroup exclusive scan over n counts -> rowptr (n+1) and cursor copy
__global__ void k_scan(const int* __restrict__ cnt, int n,
                       int* __restrict__ rowptr, int* __restrict__ cursor) {
  __shared__ int wsum[16];
  __shared__ int chunk_total;
  __shared__ int carry;
  int t = threadIdx.x;          // 1024 threads
  int lane = t & 63, w = t >> 6;
  if (t == 0) carry = 0;
  __syncthreads();
  const int CH = 8192;          // 1024 threads * 8 elems
  for (int start = 0; start < n; start += CH) {
    int base = start + t * 8;
    int v[8];
    int local = 0;
#pragma unroll
    for (int i = 0; i < 8; ++i) {
      int idx = base + i;
      int x = (idx < n) ? cnt[idx] : 0;
      v[i] = local;             // exclusive within thread
      local += x;
    }
    // inclusive scan of thread totals across the wave
    int inc = local;
#pragma unroll
    for (int off = 1; off < 64; off <<= 1) {
      int y = __shfl_up(inc, off);
      if (lane >= off) inc += y;
    }
    if (lane == 63) wsum[w] = inc;
    int excl_in_wave = inc - local;
    __syncthreads();
    if (w == 0 && lane < 16) {
      int s = wsum[lane];
      int si = s;
#pragma unroll
      for (int off = 1; off < 16; off <<= 1) {
        int y = __shfl_up(si, off);
        if (lane >= off) si += y;
      }
      wsum[lane] = si - s;      // exclusive wave offsets
      if (lane == 15) chunk_total = si;
    }
    __syncthreads();
    int mybase = carry + wsum[w] + excl_in_wave;
#pragma unroll
    for (int i = 0; i < 8; ++i) {
      int idx = base + i;
      if (idx < n) {
        int rp = mybase + v[i];
        rowptr[idx] = rp;
        cursor[idx] = rp;
      }
    }
    __syncthreads();
    if (t == 0) carry += chunk_total;
    __syncthreads();
  }
  if (t == 0) rowptr[n] = carry;
}

// pack (col, val) sorted by row
__global__ void k_scatter(const int* __restrict__ rows, const int* __restrict__ cols,
                          const float* __restrict__ vals, int nnz,
                          int* __restrict__ cursor, int2* __restrict__ epack) {
  int e = blockIdx.x * 256 + threadIdx.x;
  if (e >= nnz) return;
  int pos = atomicAdd(&cursor[rows[e]], 1);
  epack[pos] = make_int2(cols[e], __float_as_int(vals[e]));
}

// ---------------- fused gather SPMM ----------------

// one wave per row: g = sum vals*x[col]; fv = g + sign(g)*l2norm(noise)*0.1;
// optionally fout=fv; outp += fv/(3*||fv||)
__global__ void k_spmm_prop(const int* __restrict__ rowptr, const int2* __restrict__ epack,
                            const float* __restrict__ x, const float* __restrict__ noise,
                            float* __restrict__ fout, float* __restrict__ outp,
                            int n, int write_f) {
  long long t = (long long)blockIdx.x * 256 + threadIdx.x;
  int row = (int)(t >> 6), lane = (int)(t & 63);
  if (row >= n) return;
  int s = rowptr[row], e = rowptr[row + 1];
  float acc0 = 0.f, acc1 = 0.f;
  int k = s;
  for (; k + 1 < e; k += 2) {
    int2 e0 = epack[k], e1 = epack[k + 1];
    acc0 = fmaf(__int_as_float(e0.y), x[(size_t)e0.x * DD + lane], acc0);
    acc1 = fmaf(__int_as_float(e1.y), x[(size_t)e1.x * DD + lane], acc1);
  }
  if (k < e) {
    int2 e0 = epack[k];
    acc0 = fmaf(__int_as_float(e0.y), x[(size_t)e0.x * DD + lane], acc0);
  }
  float g = acc0 + acc1;
  size_t base = (size_t)row * DD + lane;
  float nz = noise[base];
  float nn = wave_sum(nz * nz);
  float nf = 0.1f / fmaxf(sqrtf(nn), 1e-12f);
  float sgn = (g > 0.f) ? 1.f : ((g < 0.f) ? -1.f : 0.f);
  float fv = g + sgn * nz * nf;
  if (write_f) fout[base] = fv;
  float fn = wave_sum(fv * fv);
  float inv = (1.f / 3.f) / fmaxf(sqrtf(fn), 1e-12f);
  outp[base] += fv * inv;
}

// aggregate: out = g + sign(g)*l2norm(noise)*0.1
__global__ void k_spmm_agg(const int* __restrict__ rowptr, const int2* __restrict__ epack,
                           const float* __restrict__ x, const float* __restrict__ noise,
                           float* __restrict__ out, int n) {
  long long t = (long long)blockIdx.x * 256 + threadIdx.x;
  int row = (int)(t >> 6), lane = (int)(t & 63);
  if (row >= n) return;
  int s = rowptr[row], e = rowptr[row + 1];
  float acc0 = 0.f, acc1 = 0.f;
  int k = s;
  for (; k + 1 < e; k += 2) {
    int2 e0 = epack[k], e1 = epack[k + 1];
    acc0 = fmaf(__int_as_float(e0.y), x[(size_t)e0.x * DD + lane], acc0);
    acc1 = fmaf(__int_as_float(e1.y), x[(size_t)e1.x * DD + lane], acc1);
  }
  if (k < e) {
    int2 e0 = epack[k];
    acc0 = fmaf(__int_as_float(e0.y), x[(size_t)e0.x * DD + lane], acc0);
  }
  float g = acc0 + acc1;
  size_t base = (size_t)row * DD + lane;
  float nz = noise[base];
  float nn = wave_sum(nz * nz);
  float nf = 0.1f / fmaxf(sqrtf(nn), 1e-12f);
  float sgn = (g > 0.f) ? 1.f : ((g < 0.f) ? -1.f : 0.f);
  out[base] = g + sgn * nz * nf;
}

// ---------------- heads ----------------

__global__ void k_bpr(const float* __restrict__ o_UI, const float* __restrict__ biu,
                      const float* __restrict__ uib, const float* __restrict__ o_BI,
                      const int* __restrict__ users, const int* __restrict__ bundles,
                      float* __restrict__ accs) {
  long long t = (long long)blockIdx.x * 256 + threadIdx.x;
  int w = (int)(t >> 6);
  int lane = (int)(t & 63);
  if (w >= BATCH) return;
  int u = users[w];
  int b0 = bundles[2 * w], b1 = bundles[2 * w + 1];
  float ur = 0.5f * (o_UI[(size_t)u * DD + lane] + biu[(size_t)u * DD + lane]);
  float br0 = 0.5f * (uib[(size_t)b0 * DD + lane] + o_BI[(size_t)b0 * DD + lane]);
  float br1 = 0.5f * (uib[(size_t)b1 * DD + lane] + o_BI[(size_t)b1 * DD + lane]);
  float pos = wave_sum(ur * br0);
  float neg = wave_sum(ur * br1);
  if (lane == 0) {
    float x = pos - neg;
    float loss = (x > 0.f) ? log1pf(expf(-x)) : (-x + log1pf(expf(x)));
    atomAddF(&accs[0], loss);
  }
}

__global__ void k_sumsq(const float* __restrict__ x, int n4, float* __restrict__ acc) {
  float s = 0.f;
  for (int i = blockIdx.x * 256 + threadIdx.x; i < n4; i += gridDim.x * 256) {
    float4 v = ((const float4*)x)[i];
    s += v.x * v.x + v.y * v.y + v.z * v.z + v.w * v.w;
  }
  s = wave_sum(s);
  __shared__ float part[4];
  if ((threadIdx.x & 63) == 0) part[threadIdx.x >> 6] = s;
  __syncthreads();
  if (threadIdx.x == 0) atomAddF(acc, part[0] + part[1] + part[2] + part[3]);
}

__global__ void k_gather(const float* __restrict__ o_UB, const float* __restrict__ o_UI,
                         const float* __restrict__ o_BI, const float* __restrict__ uib,
                         const float* __restrict__ biu, const int* __restrict__ users,
                         const int* __restrict__ bundles, float* __restrict__ P) {
  long long t = (long long)blockIdx.x * 256 + threadIdx.x;
  int w = (int)(t >> 6);
  int lane = (int)(t & 63);
  if (w >= 6 * BATCH) return;
  int k = w / BATCH, b = w % BATCH;
  const float* src;
  if (k == 0)      src = o_UB + (size_t)users[b] * DD;
  else if (k == 1) src = o_UI + (size_t)users[b] * DD;
  else if (k == 2) src = biu + (size_t)users[b] * DD;
  else if (k == 3) src = o_UB + (size_t)(U_N + bundles[2 * b]) * DD;
  else if (k == 4) src = uib + (size_t)bundles[2 * b] * DD;
  else             src = o_BI + (size_t)bundles[2 * b] * DD;
  float v = src[lane];
  float n2 = wave_sum(v * v);
  float inv = 1.f / fmaxf(sqrtf(n2), 1e-12f);
  P[(size_t)w * DD + lane] = v * inv;
}

// per (pair, 64-row i-tile): ttl_i = sum_j exp(X_i . Y_j * 4)
__global__ void k_clpair(const float* __restrict__ P, float* __restrict__ ttl) {
  __shared__ float Xs[64][65];
  __shared__ float Ys[64][65];
  const int pairX[12] = {0, 0, 1, 0, 1, 2, 3, 3, 4, 3, 4, 5};
  const int pairY[12] = {1, 2, 2, 0, 1, 2, 4, 5, 5, 3, 4, 5};
  int p = blockIdx.x >> 5;
  int it = blockIdx.x & 31;
  const float* X = P + (size_t)pairX[p] * BATCH * DD;
  const float* Y = P + (size_t)pairY[p] * BATCH * DD;
  int tx = threadIdx.x;
#pragma unroll
  for (int r = 0; r < 4; ++r) {
    int idx = tx + r * 256;
    int row = idx >> 4, c4 = idx & 15;
    float4 v = ((const float4*)(X + (size_t)(it * 64 + row) * DD))[c4];
    Xs[row][c4 * 4 + 0] = v.x; Xs[row][c4 * 4 + 1] = v.y;
    Xs[row][c4 * 4 + 2] = v.z; Xs[row][c4 * 4 + 3] = v.w;
  }
  int ti = tx & 15, tj = tx >> 4;
  float acc[4] = {0.f, 0.f, 0.f, 0.f};
  for (int jt = 0; jt < 32; ++jt) {
    __syncthreads();
#pragma unroll
    for (int r = 0; r < 4; ++r) {
      int idx = tx + r * 256;
      int row = idx >> 4, c4 = idx & 15;
      float4 v = ((const float4*)(Y + (size_t)(jt * 64 + row) * DD))[c4];
      Ys[row][c4 * 4 + 0] = v.x; Ys[row][c4 * 4 + 1] = v.y;
      Ys[row][c4 * 4 + 2] = v.z; Ys[row][c4 * 4 + 3] = v.w;
    }
    __syncthreads();
    float d[4][4];
#pragma unroll
    for (int ii = 0; ii < 4; ++ii)
#pragma unroll
      for (int jj = 0; jj < 4; ++jj) d[ii][jj] = 0.f;
    for (int k = 0; k < 64; ++k) {
      float a[4], b[4];
#pragma unroll
      for (int ii = 0; ii < 4; ++ii) a[ii] = Xs[ti * 4 + ii][k];
#pragma unroll
      for (int jj = 0; jj < 4; ++jj) b[jj] = Ys[tj * 4 + jj][k];
#pragma unroll
      for (int ii = 0; ii < 4; ++ii)
#pragma unroll
        for (int jj = 0; jj < 4; ++jj) d[ii][jj] = fmaf(a[ii], b[jj], d[ii][jj]);
    }
#pragma unroll
    for (int ii = 0; ii < 4; ++ii)
#pragma unroll
      for (int jj = 0; jj < 4; ++jj) acc[ii] += __expf(d[ii][jj] * 4.0f);
  }
  __syncthreads();
  float* red = &Xs[0][0];
#pragma unroll
  for (int ii = 0; ii < 4; ++ii) red[(ti * 4 + ii) * 17 + tj] = acc[ii];
  __syncthreads();
  if (tx < 64) {
    float s = 0.f;
#pragma unroll
    for (int t2 = 0; t2 < 16; ++t2) s += red[tx * 17 + t2];
    ttl[(size_t)p * BATCH + it * 64 + tx] = s;
  }
}

__global__ void k_cldiag(const float* __restrict__ P, const float* __restrict__ ttl,
                         float* __restrict__ accs) {
  const int pairX[12] = {0, 0, 1, 0, 1, 2, 3, 3, 4, 3, 4, 5};
  const int pairY[12] = {1, 2, 2, 0, 1, 2, 4, 5, 5, 3, 4, 5};
  long long t = (long long)blockIdx.x * 256 + threadIdx.x;
  int w = (int)(t >> 6);
  int lane = (int)(t & 63);
  if (w >= 12 * BATCH) return;
  int p = w / BATCH, i = w % BATCH;
  float xv = P[((size_t)pairX[p] * BATCH + i) * DD + lane];
  float yv = P[((size_t)pairY[p] * BATCH + i) * DD + lane];
  float d = wave_sum(xv * yv);
  if (lane == 0) {
    float term = logf(ttl[(size_t)p * BATCH + i]) - d * 4.0f;
    bool inter = (p % 6) < 3;
    atomAddF(&accs[inter ? 2 : 3], term);
  }
}

__global__ void k_final(const float* __restrict__ accs, float* __restrict__ out) {
  if (threadIdx.x == 0 && blockIdx.x == 0) {
    out[0] = accs[0] / (float)BATCH + 1e-5f * accs[1];
    out[1] = 0.04f * (0.5f * accs[2] + 0.5f * accs[3]) / (float)BATCH;
  }
}

}  // namespace

extern "C" void kernel_launch(void* const* d_in, const int* in_sizes, int n_in,
                              void* d_out, int out_size, void* d_ws, size_t ws_size,
                              hipStream_t stream) {
  const float* usersF = (const float*)d_in[0];
  const float* bundlesF = (const float*)d_in[1];
  const float* itemsF = (const float*)d_in[2];
  const int* ub_rows = (const int*)d_in[3];
  const int* ub_cols = (const int*)d_in[4];
  const float* ub_vals = (const float*)d_in[5];
  const int* ui_rows = (const int*)d_in[6];
  const int* ui_cols = (const int*)d_in[7];
  const float* ui_vals = (const float*)d_in[8];
  const int* bi_rows = (const int*)d_in[9];
  const int* bi_cols = (const int*)d_in[10];
  const float* bi_vals = (const float*)d_in[11];
  const int* biagg_rows = (const int*)d_in[12];
  const int* biagg_cols = (const int*)d_in[13];
  const float* biagg_vals = (const float*)d_in[14];
  const int* uiagg_rows = (const int*)d_in[15];
  const int* uiagg_cols = (const int*)d_in[16];
  const float* uiagg_vals = (const float*)d_in[17];
  const float* noise_UB = (const float*)d_in[18];
  const float* noise_UI = (const float*)d_in[19];
  const float* noise_BI = (const float*)d_in[20];
  const float* noise_agg_BI = (const float*)d_in[21];
  const float* noise_agg_UI = (const float*)d_in[22];
  const int* users = (const int*)d_in[23];
  const int* bundles = (const int*)d_in[24];
  int nnz_ub = in_sizes[3], nnz_ui = in_sizes[6], nnz_bi = in_sizes[9];
  int nnz_biagg = in_sizes[12], nnz_uiagg = in_sizes[15];

  float* ws = (float*)d_ws;
  size_t off = 0;
  float* o_UB = ws + off; off += (size_t)(U_N + B_N) * DD;
  float* o_UI = ws + off; off += (size_t)(U_N + I_N) * DD;
  float* o_BI = ws + off; off += (size_t)(B_N + I_N) * DD;
  float* uib  = ws + off; off += (size_t)B_N * DD;
  float* biu  = ws + off; off += (size_t)U_N * DD;
  float* s1   = ws + off; off += (size_t)(U_N + I_N) * DD;
  float* s2   = ws + off; off += (size_t)(U_N + I_N) * DD;
  float* P    = ws + off; off += (size_t)6 * BATCH * DD;
  float* ttl  = ws + off; off += (size_t)12 * BATCH;
  float* accs = ws + off; off += 8;
  int* cnt    = (int*)(ws + off); off += MAX_N + 1;
  int* rowptr = (int*)(ws + off); off += MAX_N + 2;
  int* cursor = (int*)(ws + off); off += MAX_N + 1;
  off = (off + 1) & ~(size_t)1;  // 8B align for int2
  int2* epack = (int2*)(ws + off); off += (size_t)MAX_NNZ * 2;
  if (ws_size < off * sizeof(float)) return;  // insufficient workspace

  hipMemsetAsync(accs, 0, 8 * sizeof(float), stream);

  auto build_csr = [&](const int* rws, const int* cls, const float* vls, int nnz, int n) {
    hipMemsetAsync(cnt, 0, (size_t)n * sizeof(int), stream);
    k_hist<<<(nnz + 255) / 256, 256, 0, stream>>>(rws, nnz, cnt);
    k_scan<<<1, 1024, 0, stream>>>(cnt, n, rowptr, cursor);
    k_scatter<<<(nnz + 255) / 256, 256, 0, stream>>>(rws, cls, vls, nnz, cursor, epack);
  };

  auto propagate = [&](const float* A, const float* Bf, int nA, int nB,
                       const int* rws, const int* cls, const float* vls, int nnz,
                       const float* noise, float* outp) {
    int n = nA + nB;
    build_csr(rws, cls, vls, nnz, n);
    int tot4 = n * (DD / 4);
    k_init<<<(tot4 + 255) / 256, 256, 0, stream>>>(A, Bf, s1, outp, nA, n);
    int gp = (int)(((long long)n * 64 + 255) / 256);
    k_spmm_prop<<<gp, 256, 0, stream>>>(rowptr, epack, s1, noise, s2, outp, n, 1);
    k_spmm_prop<<<gp, 256, 0, stream>>>(rowptr, epack, s2, noise + (size_t)n * DD,
                                        nullptr, outp, n, 0);
  };

  propagate(usersF, bundlesF, U_N, B_N, ub_rows, ub_cols, ub_vals, nnz_ub, noise_UB, o_UB);
  propagate(usersF, itemsF, U_N, I_N, ui_rows, ui_cols, ui_vals, nnz_ui, noise_UI, o_UI);
  propagate(bundlesF, itemsF, B_N, I_N, bi_rows, bi_cols, bi_vals, nnz_bi, noise_BI, o_BI);

  // UI_b = aggregate(biagg, UI_i)
  build_csr(biagg_rows, biagg_cols, biagg_vals, nnz_biagg, B_N);
  k_spmm_agg<<<(int)(((long long)B_N * 64 + 255) / 256), 256, 0, stream>>>(
      rowptr, epack, o_UI + (size_t)U_N * DD, noise_agg_BI, uib, B_N);

  // BI_u = aggregate(uiagg, BI_i)
  build_csr(uiagg_rows, uiagg_cols, uiagg_vals, nnz_uiagg, U_N);
  k_spmm_agg<<<(int)(((long long)U_N * 64 + 255) / 256), 256, 0, stream>>>(
      rowptr, epack, o_BI + (size_t)B_N * DD, noise_agg_UI, biu, U_N);

  // BPR loss
  k_bpr<<<BATCH * 64 / 256, 256, 0, stream>>>(o_UI, biu, uib, o_BI, users, bundles, accs);
  // Regularizer
  k_sumsq<<<1024, 256, 0, stream>>>(usersF, U_N * DD / 4, accs + 1);
  k_sumsq<<<1024, 256, 0, stream>>>(bundlesF, B_N * DD / 4, accs + 1);
  k_sumsq<<<1024, 256, 0, stream>>>(itemsF, I_N * DD / 4, accs + 1);
  // CL losses
  k_gather<<<6 * BATCH * 64 / 256, 256, 0, stream>>>(o_UB, o_UI, o_BI, uib, biu,
                                                     users, bundles, P);
  k_clpair<<<12 * 32, 256, 0, stream>>>(P, ttl);
  k_cldiag<<<12 * BATCH * 64 / 256, 256, 0, stream>>>(P, ttl, accs);
  k_final<<<1, 64, 0, stream>>>(accs, (float*)d_out);
}

// Round 3
// 2469.902 us; speedup vs baseline: 4.6021x; 1.2729x over previous
//
#include <hip/hip_runtime.h>
#include <cmath>

#define DD 64

namespace {

constexpr int U_N = 50000, B_N = 20000, I_N = 100000;
constexpr int BATCH = 2048;

__device__ __forceinline__ float wave_sum(float v) {
#pragma unroll
  for (int off = 32; off > 0; off >>= 1) v += __shfl_xor(v, off);
  return v;
}

// out = concat(A, Bf) * (1/3)   (layer-0 term, unnormalized)
__global__ void k_init0(const float* __restrict__ A, const float* __restrict__ Bf,
                        float* __restrict__ out, int nA, int nTot) {
  int idx = blockIdx.x * 256 + threadIdx.x;
  int tot4 = nTot * (DD / 4);
  if (idx >= tot4) return;
  int nA4 = nA * (DD / 4);
  float4 v = (idx < nA4) ? ((const float4*)A)[idx] : ((const float4*)Bf)[idx - nA4];
  float4 o;
  o.x = v.x * (1.f / 3.f); o.y = v.y * (1.f / 3.f);
  o.z = v.z * (1.f / 3.f); o.w = v.w * (1.f / 3.f);
  ((float4*)out)[idx] = o;
}

// ---------------- CSR build ----------------

__global__ void k_hist(const int* __restrict__ rows, int nnz, int* __restrict__ cnt) {
  int e = blockIdx.x * 256 + threadIdx.x;
  if (e < nnz) atomicAdd(&cnt[rows[e]], 1);
}

struct ScanJob { const int* cnt; int* rowptr; int* cursor; int n; };
struct ScanJobs { ScanJob j[5]; };

// one workgroup per job: exclusive scan cnt -> rowptr; cursor gets same values
// (cursor may alias cnt: each element is read before being overwritten)
__global__ void k_scan5(ScanJobs jobs) {
  ScanJob jb = jobs.j[blockIdx.x];
  const int* cnt = jb.cnt;
  int* rowptr = jb.rowptr;
  int* cursor = jb.cursor;
  int n = jb.n;
  __shared__ int wsum[16];
  __shared__ int chunk_total;
  __shared__ int carry;
  int t = threadIdx.x;          // 1024 threads
  int lane = t & 63, w = t >> 6;
  if (t == 0) carry = 0;
  __syncthreads();
  const int CH = 8192;          // 1024 threads * 8 elems
  for (int start = 0; start < n; start += CH) {
    int base = start + t * 8;
    int v[8];
    int local = 0;
#pragma unroll
    for (int i = 0; i < 8; ++i) {
      int idx = base + i;
      int x = (idx < n) ? cnt[idx] : 0;
      v[i] = local;             // exclusive within thread
      local += x;
    }
    int inc = local;
#pragma unroll
    for (int off = 1; off < 64; off <<= 1) {
      int y = __shfl_up(inc, off);
      if (lane >= off) inc += y;
    }
    if (lane == 63) wsum[w] = inc;
    int excl_in_wave = inc - local;
    __syncthreads();
    if (w == 0 && lane < 16) {
      int s = wsum[lane];
      int si = s;
#pragma unroll
      for (int off = 1; off < 16; off <<= 1) {
        int y = __shfl_up(si, off);
        if (lane >= off) si += y;
      }
      wsum[lane] = si - s;
      if (lane == 15) chunk_total = si;
    }
    __syncthreads();
    int mybase = carry + wsum[w] + excl_in_wave;
#pragma unroll
    for (int i = 0; i < 8; ++i) {
      int idx = base + i;
      if (idx < n) {
        int rp = mybase + v[i];
        rowptr[idx] = rp;
        cursor[idx] = rp;
      }
    }
    __syncthreads();
    if (t == 0) carry += chunk_total;
    __syncthreads();
  }
  if (t == 0) rowptr[n] = carry;
}

__global__ void k_scatter(const int* __restrict__ rows, const int* __restrict__ cols,
                          const float* __restrict__ vals, int nnz,
                          int* __restrict__ cursor, int2* __restrict__ epack) {
  int e = blockIdx.x * 256 + threadIdx.x;
  if (e >= nnz) return;
  int pos = atomicAdd(&cursor[rows[e]], 1);
  epack[pos] = make_int2(cols[e], __float_as_int(vals[e]));
}

// ---------------- fused gather SPMM ----------------

// one wave per row: g = sum vals*x[col] (x split as xA|xB at nA);
// fv = g + sign(g)*l2norm(noise)*0.1; optionally fout=fv; outp += fv/(3*||fv||)
__global__ void k_spmm_prop(const int* __restrict__ rowptr, const int2* __restrict__ epack,
                            const float* __restrict__ xA, const float* __restrict__ xB,
                            int nA, const float* __restrict__ noise,
                            float* __restrict__ fout, float* __restrict__ outp,
                            int n, int write_f) {
  long long t = (long long)blockIdx.x * 256 + threadIdx.x;
  int row = (int)(t >> 6), lane = (int)(t & 63);
  if (row >= n) return;
  int s = rowptr[row], e = rowptr[row + 1];
  float acc0 = 0.f, acc1 = 0.f;
  int k = s;
  for (; k + 1 < e; k += 2) {
    int2 e0 = epack[k], e1 = epack[k + 1];
    const float* x0 = (e0.x < nA) ? (xA + (size_t)e0.x * DD)
                                  : (xB + (size_t)(e0.x - nA) * DD);
    const float* x1 = (e1.x < nA) ? (xA + (size_t)e1.x * DD)
                                  : (xB + (size_t)(e1.x - nA) * DD);
    acc0 = fmaf(__int_as_float(e0.y), x0[lane], acc0);
    acc1 = fmaf(__int_as_float(e1.y), x1[lane], acc1);
  }
  if (k < e) {
    int2 e0 = epack[k];
    const float* x0 = (e0.x < nA) ? (xA + (size_t)e0.x * DD)
                                  : (xB + (size_t)(e0.x - nA) * DD);
    acc0 = fmaf(__int_as_float(e0.y), x0[lane], acc0);
  }
  float g = acc0 + acc1;
  size_t base = (size_t)row * DD + lane;
  float nz = noise[base];
  float nn = wave_sum(nz * nz);
  float nf = 0.1f / fmaxf(sqrtf(nn), 1e-12f);
  float sgn = (g > 0.f) ? 1.f : ((g < 0.f) ? -1.f : 0.f);
  float fv = g + sgn * nz * nf;
  if (write_f) fout[base] = fv;
  float fn = wave_sum(fv * fv);
  float inv = (1.f / 3.f) / fmaxf(sqrtf(fn), 1e-12f);
  outp[base] += fv * inv;
}

// aggregate: out = g + sign(g)*l2norm(noise)*0.1
__global__ void k_spmm_agg(const int* __restrict__ rowptr, const int2* __restrict__ epack,
                           const float* __restrict__ x, const float* __restrict__ noise,
                           float* __restrict__ out, int n) {
  long long t = (long long)blockIdx.x * 256 + threadIdx.x;
  int row = (int)(t >> 6), lane = (int)(t & 63);
  if (row >= n) return;
  int s = rowptr[row], e = rowptr[row + 1];
  float acc0 = 0.f, acc1 = 0.f;
  int k = s;
  for (; k + 1 < e; k += 2) {
    int2 e0 = epack[k], e1 = epack[k + 1];
    acc0 = fmaf(__int_as_float(e0.y), x[(size_t)e0.x * DD + lane], acc0);
    acc1 = fmaf(__int_as_float(e1.y), x[(size_t)e1.x * DD + lane], acc1);
  }
  if (k < e) {
    int2 e0 = epack[k];
    acc0 = fmaf(__int_as_float(e0.y), x[(size_t)e0.x * DD + lane], acc0);
  }
  float g = acc0 + acc1;
  size_t base = (size_t)row * DD + lane;
  float nz = noise[base];
  float nn = wave_sum(nz * nz);
  float nf = 0.1f / fmaxf(sqrtf(nn), 1e-12f);
  float sgn = (g > 0.f) ? 1.f : ((g < 0.f) ? -1.f : 0.f);
  out[base] = g + sgn * nz * nf;
}

// ---------------- heads (no contended atomics) ----------------

__global__ void k_bpr(const float* __restrict__ o_UI, const float* __restrict__ biu,
                      const float* __restrict__ uib, const float* __restrict__ o_BI,
                      const int* __restrict__ users, const int* __restrict__ bundles,
                      float* __restrict__ bpr_terms) {
  long long t = (long long)blockIdx.x * 256 + threadIdx.x;
  int w = (int)(t >> 6);
  int lane = (int)(t & 63);
  if (w >= BATCH) return;
  int u = users[w];
  int b0 = bundles[2 * w], b1 = bundles[2 * w + 1];
  float ur = 0.5f * (o_UI[(size_t)u * DD + lane] + biu[(size_t)u * DD + lane]);
  float br0 = 0.5f * (uib[(size_t)b0 * DD + lane] + o_BI[(size_t)b0 * DD + lane]);
  float br1 = 0.5f * (uib[(size_t)b1 * DD + lane] + o_BI[(size_t)b1 * DD + lane]);
  float pos = wave_sum(ur * br0);
  float neg = wave_sum(ur * br1);
  if (lane == 0) {
    float x = pos - neg;
    float loss = (x > 0.f) ? log1pf(expf(-x)) : (-x + log1pf(expf(x)));
    bpr_terms[w] = loss;
  }
}

__global__ void k_sumsq_p(const float* __restrict__ x, int n4, float* __restrict__ partials) {
  float s = 0.f;
  for (int i = blockIdx.x * 256 + threadIdx.x; i < n4; i += gridDim.x * 256) {
    float4 v = ((const float4*)x)[i];
    s += v.x * v.x + v.y * v.y + v.z * v.z + v.w * v.w;
  }
  s = wave_sum(s);
  __shared__ float part[4];
  if ((threadIdx.x & 63) == 0) part[threadIdx.x >> 6] = s;
  __syncthreads();
  if (threadIdx.x == 0) partials[blockIdx.x] = part[0] + part[1] + part[2] + part[3];
}

__global__ void k_gather(const float* __restrict__ o_UB, const float* __restrict__ o_UI,
                         const float* __restrict__ o_BI, const float* __restrict__ uib,
                         const float* __restrict__ biu, const int* __restrict__ users,
                         const int* __restrict__ bundles, float* __restrict__ P) {
  long long t = (long long)blockIdx.x * 256 + threadIdx.x;
  int w = (int)(t >> 6);
  int lane = (int)(t & 63);
  if (w >= 6 * BATCH) return;
  int k = w / BATCH, b = w % BATCH;
  const float* src;
  if (k == 0)      src = o_UB + (size_t)users[b] * DD;
  else if (k == 1) src = o_UI + (size_t)users[b] * DD;
  else if (k == 2) src = biu + (size_t)users[b] * DD;
  else if (k == 3) src = o_UB + (size_t)(U_N + bundles[2 * b]) * DD;
  else if (k == 4) src = uib + (size_t)bundles[2 * b] * DD;
  else             src = o_BI + (size_t)bundles[2 * b] * DD;
  float v = src[lane];
  float n2 = wave_sum(v * v);
  float inv = 1.f / fmaxf(sqrtf(n2), 1e-12f);
  P[(size_t)w * DD + lane] = v * inv;
}

// per (pair, 64-row i-tile): ttl_i = sum_j exp(X_i . Y_j * 4)
__global__ void k_clpair(const float* __restrict__ P, float* __restrict__ ttl) {
  __shared__ float Xs[64][65];
  __shared__ float Ys[64][65];
  const int pairX[12] = {0, 0, 1, 0, 1, 2, 3, 3, 4, 3, 4, 5};
  const int pairY[12] = {1, 2, 2, 0, 1, 2, 4, 5, 5, 3, 4, 5};
  int p = blockIdx.x >> 5;
  int it = blockIdx.x & 31;
  const float* X = P + (size_t)pairX[p] * BATCH * DD;
  const float* Y = P + (size_t)pairY[p] * BATCH * DD;
  int tx = threadIdx.x;
#pragma unroll
  for (int r = 0; r < 4; ++r) {
    int idx = tx + r * 256;
    int row = idx >> 4, c4 = idx & 15;
    float4 v = ((const float4*)(X + (size_t)(it * 64 + row) * DD))[c4];
    Xs[row][c4 * 4 + 0] = v.x; Xs[row][c4 * 4 + 1] = v.y;
    Xs[row][c4 * 4 + 2] = v.z; Xs[row][c4 * 4 + 3] = v.w;
  }
  int ti = tx & 15, tj = tx >> 4;
  float acc[4] = {0.f, 0.f, 0.f, 0.f};
  for (int jt = 0; jt < 32; ++jt) {
    __syncthreads();
#pragma unroll
    for (int r = 0; r < 4; ++r) {
      int idx = tx + r * 256;
      int row = idx >> 4, c4 = idx & 15;
      float4 v = ((const float4*)(Y + (size_t)(jt * 64 + row) * DD))[c4];
      Ys[row][c4 * 4 + 0] = v.x; Ys[row][c4 * 4 + 1] = v.y;
      Ys[row][c4 * 4 + 2] = v.z; Ys[row][c4 * 4 + 3] = v.w;
    }
    __syncthreads();
    float d[4][4];
#pragma unroll
    for (int ii = 0; ii < 4; ++ii)
#pragma unroll
      for (int jj = 0; jj < 4; ++jj) d[ii][jj] = 0.f;
    for (int k = 0; k < 64; ++k) {
      float a[4], b[4];
#pragma unroll
      for (int ii = 0; ii < 4; ++ii) a[ii] = Xs[ti * 4 + ii][k];
#pragma unroll
      for (int jj = 0; jj < 4; ++jj) b[jj] = Ys[tj * 4 + jj][k];
#pragma unroll
      for (int ii = 0; ii < 4; ++ii)
#pragma unroll
        for (int jj = 0; jj < 4; ++jj) d[ii][jj] = fmaf(a[ii], b[jj], d[ii][jj]);
    }
#pragma unroll
    for (int ii = 0; ii < 4; ++ii)
#pragma unroll
      for (int jj = 0; jj < 4; ++jj) acc[ii] += __expf(d[ii][jj] * 4.0f);
  }
  __syncthreads();
  float* red = &Xs[0][0];
#pragma unroll
  for (int ii = 0; ii < 4; ++ii) red[(ti * 4 + ii) * 17 + tj] = acc[ii];
  __syncthreads();
  if (tx < 64) {
    float s = 0.f;
#pragma unroll
    for (int t2 = 0; t2 < 16; ++t2) s += red[tx * 17 + t2];
    ttl[(size_t)p * BATCH + it * 64 + tx] = s;
  }
}

// per (pair, i): ttl[p,i] <- log(ttl[p,i]) - diag/tau  (in place, no atomics)
__global__ void k_cldiag(const float* __restrict__ P, float* __restrict__ ttl) {
  const int pairX[12] = {0, 0, 1, 0, 1, 2, 3, 3, 4, 3, 4, 5};
  const int pairY[12] = {1, 2, 2, 0, 1, 2, 4, 5, 5, 3, 4, 5};
  long long t = (long long)blockIdx.x * 256 + threadIdx.x;
  int w = (int)(t >> 6);
  int lane = (int)(t & 63);
  if (w >= 12 * BATCH) return;
  int p = w / BATCH, i = w % BATCH;
  float xv = P[((size_t)pairX[p] * BATCH + i) * DD + lane];
  float yv = P[((size_t)pairY[p] * BATCH + i) * DD + lane];
  float d = wave_sum(xv * yv);
  if (lane == 0) ttl[(size_t)p * BATCH + i] = logf(ttl[(size_t)p * BATCH + i]) - d * 4.0f;
}

// single block: combine bpr_terms, cl terms, sumsq partials -> out[0..1]
__global__ void k_finalred(const float* __restrict__ bpr_terms,
                           const float* __restrict__ cl_terms,
                           const float* __restrict__ partials,
                           float* __restrict__ out) {
  int t = threadIdx.x;  // 1024
  float bpr = 0.f, reg = 0.f, inter = 0.f, intra = 0.f;
  for (int i = t; i < BATCH; i += 1024) bpr += bpr_terms[i];
  for (int i = t; i < 768; i += 1024) reg += partials[i];
  for (int i = t; i < 12 * BATCH; i += 1024) {
    int p = i >> 11;
    float v = cl_terms[i];
    if ((p % 6) < 3) inter += v; else intra += v;
  }
  bpr = wave_sum(bpr); reg = wave_sum(reg);
  inter = wave_sum(inter); intra = wave_sum(intra);
  __shared__ float sb[16], sr[16], si[16], sx[16];
  int w = t >> 6, lane = t & 63;
  if (lane == 0) { sb[w] = bpr; sr[w] = reg; si[w] = inter; sx[w] = intra; }
  __syncthreads();
  if (t == 0) {
    float Bs = 0, Rs = 0, Is = 0, Xs = 0;
    for (int i = 0; i < 16; ++i) { Bs += sb[i]; Rs += sr[i]; Is += si[i]; Xs += sx[i]; }
    out[0] = Bs / (float)BATCH + 1e-5f * Rs;
    out[1] = 0.04f * (0.5f * Is + 0.5f * Xs) / (float)BATCH;
  }
}

}  // namespace

extern "C" void kernel_launch(void* const* d_in, const int* in_sizes, int n_in,
                              void* d_out, int out_size, void* d_ws, size_t ws_size,
                              hipStream_t stream) {
  const float* usersF = (const float*)d_in[0];
  const float* bundlesF = (const float*)d_in[1];
  const float* itemsF = (const float*)d_in[2];
  const int* ub_rows = (const int*)d_in[3];
  const int* ub_cols = (const int*)d_in[4];
  const float* ub_vals = (const float*)d_in[5];
  const int* ui_rows = (const int*)d_in[6];
  const int* ui_cols = (const int*)d_in[7];
  const float* ui_vals = (const float*)d_in[8];
  const int* bi_rows = (const int*)d_in[9];
  const int* bi_cols = (const int*)d_in[10];
  const float* bi_vals = (const float*)d_in[11];
  const int* biagg_rows = (const int*)d_in[12];
  const int* biagg_cols = (const int*)d_in[13];
  const float* biagg_vals = (const float*)d_in[14];
  const int* uiagg_rows = (const int*)d_in[15];
  const int* uiagg_cols = (const int*)d_in[16];
  const float* uiagg_vals = (const float*)d_in[17];
  const float* noise_UB = (const float*)d_in[18];
  const float* noise_UI = (const float*)d_in[19];
  const float* noise_BI = (const float*)d_in[20];
  const float* noise_agg_BI = (const float*)d_in[21];
  const float* noise_agg_UI = (const float*)d_in[22];
  const int* users = (const int*)d_in[23];
  const int* bundles = (const int*)d_in[24];
  int nnz_ub = in_sizes[3], nnz_ui = in_sizes[6], nnz_bi = in_sizes[9];
  int nnz_biagg = in_sizes[12], nnz_uiagg = in_sizes[15];

  float* ws = (float*)d_ws;
  size_t off = 0;
  float* o_UB = ws + off; off += (size_t)(U_N + B_N) * DD;
  float* o_UI = ws + off; off += (size_t)(U_N + I_N) * DD;
  float* o_BI = ws + off; off += (size_t)(B_N + I_N) * DD;
  float* uib  = ws + off; off += (size_t)B_N * DD;
  float* biu  = ws + off; off += (size_t)U_N * DD;
  float* s2   = ws + off; off += (size_t)(U_N + I_N) * DD;
  float* P    = ws + off; off += (size_t)6 * BATCH * DD;
  float* ttl  = ws + off; off += (size_t)12 * BATCH;
  float* bprT = ws + off; off += BATCH;
  float* prt  = ws + off; off += 768;
  // CSR buffers: phase 1 = {UB, UI, BI}; phase 2 = {BIAGG, UIAGG} (reused)
  constexpr int CNT_TOT = 340000;    // 70000 + 150000 + 120000
  int* cnt    = (int*)(ws + off); off += CNT_TOT;
  int* rptr   = (int*)(ws + off); off += 340008;
  off = (off + 1) & ~(size_t)1;
  int2* epack = (int2*)(ws + off); off += (size_t)5200000 * 2;
  if (ws_size < off * sizeof(float)) return;  // insufficient workspace

  // phase-1 CSR: all three propagate graphs
  int* cnt_ub = cnt,           * cnt_ui = cnt + 70000,  * cnt_bi = cnt + 220000;
  int* rp_ub  = rptr,          * rp_ui  = rptr + 70002, * rp_bi  = rptr + 220004;
  int2* ep_ub = epack,         * ep_ui  = epack + 1600000, * ep_bi = epack + 3600000;
  hipMemsetAsync(cnt, 0, (size_t)CNT_TOT * sizeof(int), stream);
  k_hist<<<(nnz_ub + 255) / 256, 256, 0, stream>>>(ub_rows, nnz_ub, cnt_ub);
  k_hist<<<(nnz_ui + 255) / 256, 256, 0, stream>>>(ui_rows, nnz_ui, cnt_ui);
  k_hist<<<(nnz_bi + 255) / 256, 256, 0, stream>>>(bi_rows, nnz_bi, cnt_bi);
  {
    ScanJobs jobs;
    jobs.j[0] = {cnt_ub, rp_ub, cnt_ub, U_N + B_N};
    jobs.j[1] = {cnt_ui, rp_ui, cnt_ui, U_N + I_N};
    jobs.j[2] = {cnt_bi, rp_bi, cnt_bi, B_N + I_N};
    jobs.j[3] = jobs.j[0]; jobs.j[4] = jobs.j[0];
    k_scan5<<<3, 1024, 0, stream>>>(jobs);
  }
  k_scatter<<<(nnz_ub + 255) / 256, 256, 0, stream>>>(ub_rows, ub_cols, ub_vals, nnz_ub, cnt_ub, ep_ub);
  k_scatter<<<(nnz_ui + 255) / 256, 256, 0, stream>>>(ui_rows, ui_cols, ui_vals, nnz_ui, cnt_ui, ep_ui);
  k_scatter<<<(nnz_bi + 255) / 256, 256, 0, stream>>>(bi_rows, bi_cols, bi_vals, nnz_bi, cnt_bi, ep_bi);

  auto propagate = [&](const float* A, const float* Bf, int nA, int nB,
                       const int* rp, const int2* ep, const float* noise, float* outp) {
    int n = nA + nB;
    int tot4 = n * (DD / 4);
    k_init0<<<(tot4 + 255) / 256, 256, 0, stream>>>(A, Bf, outp, nA, n);
    int gp = (int)(((long long)n * 64 + 255) / 256);
    k_spmm_prop<<<gp, 256, 0, stream>>>(rp, ep, A, Bf, nA, noise, s2, outp, n, 1);
    k_spmm_prop<<<gp, 256, 0, stream>>>(rp, ep, s2, s2, n, noise + (size_t)n * DD,
                                        nullptr, outp, n, 0);
  };

  propagate(usersF, bundlesF, U_N, B_N, rp_ub, ep_ub, noise_UB, o_UB);
  propagate(usersF, itemsF, U_N, I_N, rp_ui, ep_ui, noise_UI, o_UI);
  propagate(bundlesF, itemsF, B_N, I_N, rp_bi, ep_bi, noise_BI, o_BI);

  // phase-2 CSR: both aggregate graphs (reuse buffers; prop CSRs now dead)
  int* cnt_ba = cnt,  * cnt_ua = cnt + 20000;
  int* rp_ba  = rptr, * rp_ua  = rptr + 20002;
  int2* ep_ba = epack, * ep_ua = epack + 800000;
  hipMemsetAsync(cnt, 0, (size_t)(B_N + U_N) * sizeof(int), stream);
  k_hist<<<(nnz_biagg + 255) / 256, 256, 0, stream>>>(biagg_rows, nnz_biagg, cnt_ba);
  k_hist<<<(nnz_uiagg + 255) / 256, 256, 0, stream>>>(uiagg_rows, nnz_uiagg, cnt_ua);
  {
    ScanJobs jobs;
    jobs.j[0] = {cnt_ba, rp_ba, cnt_ba, B_N};
    jobs.j[1] = {cnt_ua, rp_ua, cnt_ua, U_N};
    jobs.j[2] = jobs.j[0]; jobs.j[3] = jobs.j[0]; jobs.j[4] = jobs.j[0];
    k_scan5<<<2, 1024, 0, stream>>>(jobs);
  }
  k_scatter<<<(nnz_biagg + 255) / 256, 256, 0, stream>>>(biagg_rows, biagg_cols, biagg_vals,
                                                         nnz_biagg, cnt_ba, ep_ba);
  k_scatter<<<(nnz_uiagg + 255) / 256, 256, 0, stream>>>(uiagg_rows, uiagg_cols, uiagg_vals,
                                                         nnz_uiagg, cnt_ua, ep_ua);
  k_spmm_agg<<<(int)(((long long)B_N * 64 + 255) / 256), 256, 0, stream>>>(
      rp_ba, ep_ba, o_UI + (size_t)U_N * DD, noise_agg_BI, uib, B_N);
  k_spmm_agg<<<(int)(((long long)U_N * 64 + 255) / 256), 256, 0, stream>>>(
      rp_ua, ep_ua, o_BI + (size_t)B_N * DD, noise_agg_UI, biu, U_N);

  // heads
  k_bpr<<<BATCH * 64 / 256, 256, 0, stream>>>(o_UI, biu, uib, o_BI, users, bundles, bprT);
  k_sumsq_p<<<256, 256, 0, stream>>>(usersF, U_N * DD / 4, prt);
  k_sumsq_p<<<256, 256, 0, stream>>>(bundlesF, B_N * DD / 4, prt + 256);
  k_sumsq_p<<<256, 256, 0, stream>>>(itemsF, I_N * DD / 4, prt + 512);
  k_gather<<<6 * BATCH * 64 / 256, 256, 0, stream>>>(o_UB, o_UI, o_BI, uib, biu,
                                                     users, bundles, P);
  k_clpair<<<12 * 32, 256, 0, stream>>>(P, ttl);
  k_cldiag<<<12 * BATCH * 64 / 256, 256, 0, stream>>>(P, ttl);
  k_finalred<<<1, 1024, 0, stream>>>(bprT, ttl, prt, (float*)d_out);
}

// Round 4
// 2222.960 us; speedup vs baseline: 5.1134x; 1.1111x over previous
//
#include <hip/hip_runtime.h>
#include <cmath>

#define DD 64

namespace {

constexpr int U_N = 50000, B_N = 20000, I_N = 100000;
constexpr int BATCH = 2048;
constexpr int SCAN_ELEMS = 2048;  // per block: 256 threads x 8

__device__ __forceinline__ float wave_sum(float v) {
#pragma unroll
  for (int off = 32; off > 0; off >>= 1) v += __shfl_xor(v, off);
  return v;
}

// out = concat(A, Bf) * (1/3)   (layer-0 term, unnormalized)
__global__ void k_init0(const float* __restrict__ A, const float* __restrict__ Bf,
                        float* __restrict__ out, int nA, int nTot) {
  int idx = blockIdx.x * 256 + threadIdx.x;
  int tot4 = nTot * (DD / 4);
  if (idx >= tot4) return;
  int nA4 = nA * (DD / 4);
  float4 v = (idx < nA4) ? ((const float4*)A)[idx] : ((const float4*)Bf)[idx - nA4];
  float4 o;
  o.x = v.x * (1.f / 3.f); o.y = v.y * (1.f / 3.f);
  o.z = v.z * (1.f / 3.f); o.w = v.w * (1.f / 3.f);
  ((float4*)out)[idx] = o;
}

// ---------------- CSR build (multi-block scan) ----------------

__global__ void k_hist(const int* __restrict__ rows, int nnz, int* __restrict__ cnt) {
  int e = blockIdx.x * 256 + threadIdx.x;
  if (e < nnz) atomicAdd(&cnt[rows[e]], 1);
}

// block sums over SCAN_ELEMS-chunks
__global__ void k_psum(const int* __restrict__ cnt, int n, int* __restrict__ bsum) {
  int t = threadIdx.x;
  int base = blockIdx.x * SCAN_ELEMS + t * 8;
  int s = 0;
#pragma unroll
  for (int i = 0; i < 8; ++i) {
    int idx = base + i;
    if (idx < n) s += cnt[idx];
  }
#pragma unroll
  for (int off = 32; off > 0; off >>= 1) s += __shfl_xor(s, off);
  __shared__ int part[4];
  if ((t & 63) == 0) part[t >> 6] = s;
  __syncthreads();
  if (t == 0) bsum[blockIdx.x] = part[0] + part[1] + part[2] + part[3];
}

// single 256-thread block: exclusive scan of <=256 block sums; total -> *total_dst
__global__ void k_bscan(const int* __restrict__ bsum, int nb, int* __restrict__ boff,
                        int* __restrict__ total_dst) {
  int t = threadIdx.x;  // 256
  int lane = t & 63, w = t >> 6;
  int v = (t < nb) ? bsum[t] : 0;
  int inc = v;
#pragma unroll
  for (int off = 1; off < 64; off <<= 1) {
    int y = __shfl_up(inc, off);
    if (lane >= off) inc += y;
  }
  __shared__ int ws[4];
  if (lane == 63) ws[w] = inc;
  __syncthreads();
  int wadd = 0;
  for (int i = 0; i < w; ++i) wadd += ws[i];
  inc += wadd;
  if (t < nb) boff[t] = inc - v;
  if (t == 255) *total_dst = inc;
}

// per-block local exclusive scan + block offset -> rowptr, cursor (cursor may alias cnt)
__global__ void k_apply(const int* __restrict__ cnt, int n, const int* __restrict__ boff,
                        int* __restrict__ rowptr, int* __restrict__ cursor) {
  int t = threadIdx.x;
  int lane = t & 63, w = t >> 6;
  int base = blockIdx.x * SCAN_ELEMS + t * 8;
  int v[8];
  int local = 0;
#pragma unroll
  for (int i = 0; i < 8; ++i) {
    int idx = base + i;
    int x = (idx < n) ? cnt[idx] : 0;
    v[i] = local;
    local += x;
  }
  int inc = local;
#pragma unroll
  for (int off = 1; off < 64; off <<= 1) {
    int y = __shfl_up(inc, off);
    if (lane >= off) inc += y;
  }
  __shared__ int ws[4];
  if (lane == 63) ws[w] = inc;
  __syncthreads();
  int wadd = 0;
  for (int i = 0; i < w; ++i) wadd += ws[i];
  int mybase = boff[blockIdx.x] + wadd + (inc - local);
#pragma unroll
  for (int i = 0; i < 8; ++i) {
    int idx = base + i;
    if (idx < n) {
      int rp = mybase + v[i];
      rowptr[idx] = rp;
      cursor[idx] = rp;
    }
  }
}

__global__ void k_scatter(const int* __restrict__ rows, const int* __restrict__ cols,
                          const float* __restrict__ vals, int nnz,
                          int* __restrict__ cursor, int2* __restrict__ epack) {
  int e = blockIdx.x * 256 + threadIdx.x;
  if (e >= nnz) return;
  int pos = atomicAdd(&cursor[rows[e]], 1);
  epack[pos] = make_int2(cols[e], __float_as_int(vals[e]));
}

// ---------------- fused gather SPMM ----------------

__global__ void k_spmm_prop(const int* __restrict__ rowptr, const int2* __restrict__ epack,
                            const float* __restrict__ xA, const float* __restrict__ xB,
                            int nA, const float* __restrict__ noise,
                            float* __restrict__ fout, float* __restrict__ outp,
                            int n, int write_f) {
  long long t = (long long)blockIdx.x * 256 + threadIdx.x;
  int row = (int)(t >> 6), lane = (int)(t & 63);
  if (row >= n) return;
  int s = rowptr[row], e = rowptr[row + 1];
  float acc0 = 0.f, acc1 = 0.f;
  int k = s;
  for (; k + 1 < e; k += 2) {
    int2 e0 = epack[k], e1 = epack[k + 1];
    const float* x0 = (e0.x < nA) ? (xA + (size_t)e0.x * DD)
                                  : (xB + (size_t)(e0.x - nA) * DD);
    const float* x1 = (e1.x < nA) ? (xA + (size_t)e1.x * DD)
                                  : (xB + (size_t)(e1.x - nA) * DD);
    acc0 = fmaf(__int_as_float(e0.y), x0[lane], acc0);
    acc1 = fmaf(__int_as_float(e1.y), x1[lane], acc1);
  }
  if (k < e) {
    int2 e0 = epack[k];
    const float* x0 = (e0.x < nA) ? (xA + (size_t)e0.x * DD)
                                  : (xB + (size_t)(e0.x - nA) * DD);
    acc0 = fmaf(__int_as_float(e0.y), x0[lane], acc0);
  }
  float g = acc0 + acc1;
  size_t base = (size_t)row * DD + lane;
  float nz = noise[base];
  float nn = wave_sum(nz * nz);
  float nf = 0.1f / fmaxf(sqrtf(nn), 1e-12f);
  float sgn = (g > 0.f) ? 1.f : ((g < 0.f) ? -1.f : 0.f);
  float fv = g + sgn * nz * nf;
  if (write_f) fout[base] = fv;
  float fn = wave_sum(fv * fv);
  float inv = (1.f / 3.f) / fmaxf(sqrtf(fn), 1e-12f);
  outp[base] += fv * inv;
}

__global__ void k_spmm_agg(const int* __restrict__ rowptr, const int2* __restrict__ epack,
                           const float* __restrict__ x, const float* __restrict__ noise,
                           float* __restrict__ out, int n) {
  long long t = (long long)blockIdx.x * 256 + threadIdx.x;
  int row = (int)(t >> 6), lane = (int)(t & 63);
  if (row >= n) return;
  int s = rowptr[row], e = rowptr[row + 1];
  float acc0 = 0.f, acc1 = 0.f;
  int k = s;
  for (; k + 1 < e; k += 2) {
    int2 e0 = epack[k], e1 = epack[k + 1];
    acc0 = fmaf(__int_as_float(e0.y), x[(size_t)e0.x * DD + lane], acc0);
    acc1 = fmaf(__int_as_float(e1.y), x[(size_t)e1.x * DD + lane], acc1);
  }
  if (k < e) {
    int2 e0 = epack[k];
    acc0 = fmaf(__int_as_float(e0.y), x[(size_t)e0.x * DD + lane], acc0);
  }
  float g = acc0 + acc1;
  size_t base = (size_t)row * DD + lane;
  float nz = noise[base];
  float nn = wave_sum(nz * nz);
  float nf = 0.1f / fmaxf(sqrtf(nn), 1e-12f);
  float sgn = (g > 0.f) ? 1.f : ((g < 0.f) ? -1.f : 0.f);
  out[base] = g + sgn * nz * nf;
}

// ---------------- heads (no contended atomics) ----------------

__global__ void k_bpr(const float* __restrict__ o_UI, const float* __restrict__ biu,
                      const float* __restrict__ uib, const float* __restrict__ o_BI,
                      const int* __restrict__ users, const int* __restrict__ bundles,
                      float* __restrict__ bpr_terms) {
  long long t = (long long)blockIdx.x * 256 + threadIdx.x;
  int w = (int)(t >> 6);
  int lane = (int)(t & 63);
  if (w >= BATCH) return;
  int u = users[w];
  int b0 = bundles[2 * w], b1 = bundles[2 * w + 1];
  float ur = 0.5f * (o_UI[(size_t)u * DD + lane] + biu[(size_t)u * DD + lane]);
  float br0 = 0.5f * (uib[(size_t)b0 * DD + lane] + o_BI[(size_t)b0 * DD + lane]);
  float br1 = 0.5f * (uib[(size_t)b1 * DD + lane] + o_BI[(size_t)b1 * DD + lane]);
  float pos = wave_sum(ur * br0);
  float neg = wave_sum(ur * br1);
  if (lane == 0) {
    float x = pos - neg;
    float loss = (x > 0.f) ? log1pf(expf(-x)) : (-x + log1pf(expf(x)));
    bpr_terms[w] = loss;
  }
}

__global__ void k_sumsq_p(const float* __restrict__ x, int n4, float* __restrict__ partials) {
  float s = 0.f;
  for (int i = blockIdx.x * 256 + threadIdx.x; i < n4; i += gridDim.x * 256) {
    float4 v = ((const float4*)x)[i];
    s += v.x * v.x + v.y * v.y + v.z * v.z + v.w * v.w;
  }
  s = wave_sum(s);
  __shared__ float part[4];
  if ((threadIdx.x & 63) == 0) part[threadIdx.x >> 6] = s;
  __syncthreads();
  if (threadIdx.x == 0) partials[blockIdx.x] = part[0] + part[1] + part[2] + part[3];
}

__global__ void k_gather(const float* __restrict__ o_UB, const float* __restrict__ o_UI,
                         const float* __restrict__ o_BI, const float* __restrict__ uib,
                         const float* __restrict__ biu, const int* __restrict__ users,
                         const int* __restrict__ bundles, float* __restrict__ P) {
  long long t = (long long)blockIdx.x * 256 + threadIdx.x;
  int w = (int)(t >> 6);
  int lane = (int)(t & 63);
  if (w >= 6 * BATCH) return;
  int k = w / BATCH, b = w % BATCH;
  const float* src;
  if (k == 0)      src = o_UB + (size_t)users[b] * DD;
  else if (k == 1) src = o_UI + (size_t)users[b] * DD;
  else if (k == 2) src = biu + (size_t)users[b] * DD;
  else if (k == 3) src = o_UB + (size_t)(U_N + bundles[2 * b]) * DD;
  else if (k == 4) src = uib + (size_t)bundles[2 * b] * DD;
  else             src = o_BI + (size_t)bundles[2 * b] * DD;
  float v = src[lane];
  float n2 = wave_sum(v * v);
  float inv = 1.f / fmaxf(sqrtf(n2), 1e-12f);
  P[(size_t)w * DD + lane] = v * inv;
}

// per (pair, 64-row i-tile): ttl_i = sum_j exp(X_i . Y_j * 4)
__global__ void k_clpair(const float* __restrict__ P, float* __restrict__ ttl) {
  __shared__ float Xs[64][65];
  __shared__ float Ys[64][65];
  const int pairX[12] = {0, 0, 1, 0, 1, 2, 3, 3, 4, 3, 4, 5};
  const int pairY[12] = {1, 2, 2, 0, 1, 2, 4, 5, 5, 3, 4, 5};
  int p = blockIdx.x >> 5;
  int it = blockIdx.x & 31;
  const float* X = P + (size_t)pairX[p] * BATCH * DD;
  const float* Y = P + (size_t)pairY[p] * BATCH * DD;
  int tx = threadIdx.x;
#pragma unroll
  for (int r = 0; r < 4; ++r) {
    int idx = tx + r * 256;
    int row = idx >> 4, c4 = idx & 15;
    float4 v = ((const float4*)(X + (size_t)(it * 64 + row) * DD))[c4];
    Xs[row][c4 * 4 + 0] = v.x; Xs[row][c4 * 4 + 1] = v.y;
    Xs[row][c4 * 4 + 2] = v.z; Xs[row][c4 * 4 + 3] = v.w;
  }
  int ti = tx & 15, tj = tx >> 4;
  float acc[4] = {0.f, 0.f, 0.f, 0.f};
  for (int jt = 0; jt < 32; ++jt) {
    __syncthreads();
#pragma unroll
    for (int r = 0; r < 4; ++r) {
      int idx = tx + r * 256;
      int row = idx >> 4, c4 = idx & 15;
      float4 v = ((const float4*)(Y + (size_t)(jt * 64 + row) * DD))[c4];
      Ys[row][c4 * 4 + 0] = v.x; Ys[row][c4 * 4 + 1] = v.y;
      Ys[row][c4 * 4 + 2] = v.z; Ys[row][c4 * 4 + 3] = v.w;
    }
    __syncthreads();
    float d[4][4];
#pragma unroll
    for (int ii = 0; ii < 4; ++ii)
#pragma unroll
      for (int jj = 0; jj < 4; ++jj) d[ii][jj] = 0.f;
    for (int k = 0; k < 64; ++k) {
      float a[4], b[4];
#pragma unroll
      for (int ii = 0; ii < 4; ++ii) a[ii] = Xs[ti * 4 + ii][k];
#pragma unroll
      for (int jj = 0; jj < 4; ++jj) b[jj] = Ys[tj * 4 + jj][k];
#pragma unroll
      for (int ii = 0; ii < 4; ++ii)
#pragma unroll
        for (int jj = 0; jj < 4; ++jj) d[ii][jj] = fmaf(a[ii], b[jj], d[ii][jj]);
    }
#pragma unroll
    for (int ii = 0; ii < 4; ++ii)
#pragma unroll
      for (int jj = 0; jj < 4; ++jj) acc[ii] += __expf(d[ii][jj] * 4.0f);
  }
  __syncthreads();
  float* red = &Xs[0][0];
#pragma unroll
  for (int ii = 0; ii < 4; ++ii) red[(ti * 4 + ii) * 17 + tj] = acc[ii];
  __syncthreads();
  if (tx < 64) {
    float s = 0.f;
#pragma unroll
    for (int t2 = 0; t2 < 16; ++t2) s += red[tx * 17 + t2];
    ttl[(size_t)p * BATCH + it * 64 + tx] = s;
  }
}

// per (pair, i): ttl[p,i] <- log(ttl[p,i]) - diag/tau  (in place)
__global__ void k_cldiag(const float* __restrict__ P, float* __restrict__ ttl) {
  const int pairX[12] = {0, 0, 1, 0, 1, 2, 3, 3, 4, 3, 4, 5};
  const int pairY[12] = {1, 2, 2, 0, 1, 2, 4, 5, 5, 3, 4, 5};
  long long t = (long long)blockIdx.x * 256 + threadIdx.x;
  int w = (int)(t >> 6);
  int lane = (int)(t & 63);
  if (w >= 12 * BATCH) return;
  int p = w / BATCH, i = w % BATCH;
  float xv = P[((size_t)pairX[p] * BATCH + i) * DD + lane];
  float yv = P[((size_t)pairY[p] * BATCH + i) * DD + lane];
  float d = wave_sum(xv * yv);
  if (lane == 0) ttl[(size_t)p * BATCH + i] = logf(ttl[(size_t)p * BATCH + i]) - d * 4.0f;
}

__global__ void k_finalred(const float* __restrict__ bpr_terms,
                           const float* __restrict__ cl_terms,
                           const float* __restrict__ partials,
                           float* __restrict__ out) {
  int t = threadIdx.x;  // 1024
  float bpr = 0.f, reg = 0.f, inter = 0.f, intra = 0.f;
  for (int i = t; i < BATCH; i += 1024) bpr += bpr_terms[i];
  for (int i = t; i < 768; i += 1024) reg += partials[i];
  for (int i = t; i < 12 * BATCH; i += 1024) {
    int p = i >> 11;
    float v = cl_terms[i];
    if ((p % 6) < 3) inter += v; else intra += v;
  }
  bpr = wave_sum(bpr); reg = wave_sum(reg);
  inter = wave_sum(inter); intra = wave_sum(intra);
  __shared__ float sb[16], sr[16], si[16], sx[16];
  int w = t >> 6, lane = t & 63;
  if (lane == 0) { sb[w] = bpr; sr[w] = reg; si[w] = inter; sx[w] = intra; }
  __syncthreads();
  if (t == 0) {
    float Bs = 0, Rs = 0, Is = 0, Xs = 0;
    for (int i = 0; i < 16; ++i) { Bs += sb[i]; Rs += sr[i]; Is += si[i]; Xs += sx[i]; }
    out[0] = Bs / (float)BATCH + 1e-5f * Rs;
    out[1] = 0.04f * (0.5f * Is + 0.5f * Xs) / (float)BATCH;
  }
}

}  // namespace

extern "C" void kernel_launch(void* const* d_in, const int* in_sizes, int n_in,
                              void* d_out, int out_size, void* d_ws, size_t ws_size,
                              hipStream_t stream) {
  const float* usersF = (const float*)d_in[0];
  const float* bundlesF = (const float*)d_in[1];
  const float* itemsF = (const float*)d_in[2];
  const int* ub_rows = (const int*)d_in[3];
  const int* ub_cols = (const int*)d_in[4];
  const float* ub_vals = (const float*)d_in[5];
  const int* ui_rows = (const int*)d_in[6];
  const int* ui_cols = (const int*)d_in[7];
  const float* ui_vals = (const float*)d_in[8];
  const int* bi_rows = (const int*)d_in[9];
  const int* bi_cols = (const int*)d_in[10];
  const float* bi_vals = (const float*)d_in[11];
  const int* biagg_rows = (const int*)d_in[12];
  const int* biagg_cols = (const int*)d_in[13];
  const float* biagg_vals = (const float*)d_in[14];
  const int* uiagg_rows = (const int*)d_in[15];
  const int* uiagg_cols = (const int*)d_in[16];
  const float* uiagg_vals = (const float*)d_in[17];
  const float* noise_UB = (const float*)d_in[18];
  const float* noise_UI = (const float*)d_in[19];
  const float* noise_BI = (const float*)d_in[20];
  const float* noise_agg_BI = (const float*)d_in[21];
  const float* noise_agg_UI = (const float*)d_in[22];
  const int* users = (const int*)d_in[23];
  const int* bundles = (const int*)d_in[24];
  int nnz_ub = in_sizes[3], nnz_ui = in_sizes[6], nnz_bi = in_sizes[9];
  int nnz_biagg = in_sizes[12], nnz_uiagg = in_sizes[15];

  float* ws = (float*)d_ws;
  size_t off = 0;
  float* o_UB = ws + off; off += (size_t)(U_N + B_N) * DD;
  float* o_UI = ws + off; off += (size_t)(U_N + I_N) * DD;
  float* o_BI = ws + off; off += (size_t)(B_N + I_N) * DD;
  float* uib  = ws + off; off += (size_t)B_N * DD;
  float* biu  = ws + off; off += (size_t)U_N * DD;
  float* s2   = ws + off; off += (size_t)(U_N + I_N) * DD;
  float* P    = ws + off; off += (size_t)6 * BATCH * DD;
  float* ttl  = ws + off; off += (size_t)12 * BATCH;
  float* bprT = ws + off; off += BATCH;
  float* prt  = ws + off; off += 768;
  // CSR: phase 1 = concat{UB(70000), UI(150000), BI(120000)}; phase 2 = concat{BIAGG(20000), UIAGG(50000)}
  constexpr int N1 = 340000, N2 = 70000;
  int* cnt  = (int*)(ws + off); off += N1;        // also scatter cursor (aliased)
  int* rptr = (int*)(ws + off); off += N1 + 1;
  int* bsum = (int*)(ws + off); off += 256;
  int* boff = (int*)(ws + off); off += 256;
  off = (off + 1) & ~(size_t)1;  // 8B align
  int2* epack = (int2*)(ws + off); off += (size_t)5200000 * 2;
  if (ws_size < off * sizeof(float)) return;  // insufficient workspace

  auto scan_phase = [&](int n_total) {
    int nb = (n_total + SCAN_ELEMS - 1) / SCAN_ELEMS;  // <= 167 <= 256
    k_psum<<<nb, 256, 0, stream>>>(cnt, n_total, bsum);
    k_bscan<<<1, 256, 0, stream>>>(bsum, nb, boff, rptr + n_total);
    k_apply<<<nb, 256, 0, stream>>>(cnt, n_total, boff, rptr, cnt);
  };

  // ---- phase-1 CSR: UB rows [0,70000), UI rows [70000,220000), BI rows [220000,340000)
  int* cnt_ub = cnt,        * cnt_ui = cnt + 70000,  * cnt_bi = cnt + 220000;
  int* rp_ub  = rptr,       * rp_ui  = rptr + 70000, * rp_bi  = rptr + 220000;
  hipMemsetAsync(cnt, 0, (size_t)N1 * sizeof(int), stream);
  k_hist<<<(nnz_ub + 255) / 256, 256, 0, stream>>>(ub_rows, nnz_ub, cnt_ub);
  k_hist<<<(nnz_ui + 255) / 256, 256, 0, stream>>>(ui_rows, nnz_ui, cnt_ui);
  k_hist<<<(nnz_bi + 255) / 256, 256, 0, stream>>>(bi_rows, nnz_bi, cnt_bi);
  scan_phase(N1);
  k_scatter<<<(nnz_ub + 255) / 256, 256, 0, stream>>>(ub_rows, ub_cols, ub_vals, nnz_ub, cnt_ub, epack);
  k_scatter<<<(nnz_ui + 255) / 256, 256, 0, stream>>>(ui_rows, ui_cols, ui_vals, nnz_ui, cnt_ui, epack);
  k_scatter<<<(nnz_bi + 255) / 256, 256, 0, stream>>>(bi_rows, bi_cols, bi_vals, nnz_bi, cnt_bi, epack);

  auto propagate = [&](const float* A, const float* Bf, int nA, int nB,
                       const int* rp, const float* noise, float* outp) {
    int n = nA + nB;
    int tot4 = n * (DD / 4);
    k_init0<<<(tot4 + 255) / 256, 256, 0, stream>>>(A, Bf, outp, nA, n);
    int gp = (int)(((long long)n * 64 + 255) / 256);
    k_spmm_prop<<<gp, 256, 0, stream>>>(rp, epack, A, Bf, nA, noise, s2, outp, n, 1);
    k_spmm_prop<<<gp, 256, 0, stream>>>(rp, epack, s2, s2, n, noise + (size_t)n * DD,
                                        nullptr, outp, n, 0);
  };

  propagate(usersF, bundlesF, U_N, B_N, rp_ub, noise_UB, o_UB);
  propagate(usersF, itemsF, U_N, I_N, rp_ui, noise_UI, o_UI);
  propagate(bundlesF, itemsF, B_N, I_N, rp_bi, noise_BI, o_BI);

  // ---- phase-2 CSR: BIAGG rows [0,20000), UIAGG rows [20000,70000)
  int* cnt_ba = cnt,  * cnt_ua = cnt + 20000;
  int* rp_ba  = rptr, * rp_ua  = rptr + 20000;
  hipMemsetAsync(cnt, 0, (size_t)N2 * sizeof(int), stream);
  k_hist<<<(nnz_biagg + 255) / 256, 256, 0, stream>>>(biagg_rows, nnz_biagg, cnt_ba);
  k_hist<<<(nnz_uiagg + 255) / 256, 256, 0, stream>>>(uiagg_rows, nnz_uiagg, cnt_ua);
  scan_phase(N2);
  k_scatter<<<(nnz_biagg + 255) / 256, 256, 0, stream>>>(biagg_rows, biagg_cols, biagg_vals,
                                                         nnz_biagg, cnt_ba, epack);
  k_scatter<<<(nnz_uiagg + 255) / 256, 256, 0, stream>>>(uiagg_rows, uiagg_cols, uiagg_vals,
                                                         nnz_uiagg, cnt_ua, epack);
  k_spmm_agg<<<(int)(((long long)B_N * 64 + 255) / 256), 256, 0, stream>>>(
      rp_ba, epack, o_UI + (size_t)U_N * DD, noise_agg_BI, uib, B_N);
  k_spmm_agg<<<(int)(((long long)U_N * 64 + 255) / 256), 256, 0, stream>>>(
      rp_ua, epack, o_BI + (size_t)B_N * DD, noise_agg_UI, biu, U_N);

  // heads
  k_bpr<<<BATCH * 64 / 256, 256, 0, stream>>>(o_UI, biu, uib, o_BI, users, bundles, bprT);
  k_sumsq_p<<<256, 256, 0, stream>>>(usersF, U_N * DD / 4, prt);
  k_sumsq_p<<<256, 256, 0, stream>>>(bundlesF, B_N * DD / 4, prt + 256);
  k_sumsq_p<<<256, 256, 0, stream>>>(itemsF, I_N * DD / 4, prt + 512);
  k_gather<<<6 * BATCH * 64 / 256, 256, 0, stream>>>(o_UB, o_UI, o_BI, uib, biu,
                                                     users, bundles, P);
  k_clpair<<<12 * 32, 256, 0, stream>>>(P, ttl);
  k_cldiag<<<12 * BATCH * 64 / 256, 256, 0, stream>>>(P, ttl);
  k_finalred<<<1, 1024, 0, stream>>>(bprT, ttl, prt, (float*)d_out);
}

// Round 5
// 1749.960 us; speedup vs baseline: 6.4955x; 1.2703x over previous
//
#include <hip/hip_runtime.h>
#include <cmath>

#define DD 64

namespace {

constexpr int U_N = 50000, B_N = 20000, I_N = 100000;
constexpr int BATCH = 2048;
constexpr int SCAN_ELEMS = 2048;  // per block: 256 threads x 8

typedef __attribute__((ext_vector_type(8))) short short8;   // 8 bf16 (4 VGPRs)
typedef __attribute__((ext_vector_type(4))) float floatx4;  // 4 fp32 acc

__device__ __forceinline__ float wave_sum(float v) {
#pragma unroll
  for (int off = 32; off > 0; off >>= 1) v += __shfl_xor(v, off);
  return v;
}

__device__ __forceinline__ unsigned short f2bf(float f) {
  unsigned u = __float_as_uint(f);
  unsigned r = (u + 0x7FFFu + ((u >> 16) & 1u)) >> 16;  // RNE
  return (unsigned short)r;
}

// out = concat(A, Bf) * (1/3)   (layer-0 term, unnormalized)
__global__ void k_init0(const float* __restrict__ A, const float* __restrict__ Bf,
                        float* __restrict__ out, int nA, int nTot) {
  int idx = blockIdx.x * 256 + threadIdx.x;
  int tot4 = nTot * (DD / 4);
  if (idx >= tot4) return;
  int nA4 = nA * (DD / 4);
  float4 v = (idx < nA4) ? ((const float4*)A)[idx] : ((const float4*)Bf)[idx - nA4];
  float4 o;
  o.x = v.x * (1.f / 3.f); o.y = v.y * (1.f / 3.f);
  o.z = v.z * (1.f / 3.f); o.w = v.w * (1.f / 3.f);
  ((float4*)out)[idx] = o;
}

// ---------------- CSR build (multi-block scan) ----------------

__global__ void k_hist(const int* __restrict__ rows, int nnz, int* __restrict__ cnt) {
  int e = blockIdx.x * 256 + threadIdx.x;
  if (e < nnz) atomicAdd(&cnt[rows[e]], 1);
}

__global__ void k_psum(const int* __restrict__ cnt, int n, int* __restrict__ bsum) {
  int t = threadIdx.x;
  int base = blockIdx.x * SCAN_ELEMS + t * 8;
  int s = 0;
#pragma unroll
  for (int i = 0; i < 8; ++i) {
    int idx = base + i;
    if (idx < n) s += cnt[idx];
  }
#pragma unroll
  for (int off = 32; off > 0; off >>= 1) s += __shfl_xor(s, off);
  __shared__ int part[4];
  if ((t & 63) == 0) part[t >> 6] = s;
  __syncthreads();
  if (t == 0) bsum[blockIdx.x] = part[0] + part[1] + part[2] + part[3];
}

__global__ void k_bscan(const int* __restrict__ bsum, int nb, int* __restrict__ boff,
                        int* __restrict__ total_dst) {
  int t = threadIdx.x;  // 256
  int lane = t & 63, w = t >> 6;
  int v = (t < nb) ? bsum[t] : 0;
  int inc = v;
#pragma unroll
  for (int off = 1; off < 64; off <<= 1) {
    int y = __shfl_up(inc, off);
    if (lane >= off) inc += y;
  }
  __shared__ int ws[4];
  if (lane == 63) ws[w] = inc;
  __syncthreads();
  int wadd = 0;
  for (int i = 0; i < w; ++i) wadd += ws[i];
  inc += wadd;
  if (t < nb) boff[t] = inc - v;
  if (t == 255) *total_dst = inc;
}

__global__ void k_apply(const int* __restrict__ cnt, int n, const int* __restrict__ boff,
                        int* __restrict__ rowptr, int* __restrict__ cursor) {
  int t = threadIdx.x;
  int lane = t & 63, w = t >> 6;
  int base = blockIdx.x * SCAN_ELEMS + t * 8;
  int v[8];
  int local = 0;
#pragma unroll
  for (int i = 0; i < 8; ++i) {
    int idx = base + i;
    int x = (idx < n) ? cnt[idx] : 0;
    v[i] = local;
    local += x;
  }
  int inc = local;
#pragma unroll
  for (int off = 1; off < 64; off <<= 1) {
    int y = __shfl_up(inc, off);
    if (lane >= off) inc += y;
  }
  __shared__ int ws[4];
  if (lane == 63) ws[w] = inc;
  __syncthreads();
  int wadd = 0;
  for (int i = 0; i < w; ++i) wadd += ws[i];
  int mybase = boff[blockIdx.x] + wadd + (inc - local);
#pragma unroll
  for (int i = 0; i < 8; ++i) {
    int idx = base + i;
    if (idx < n) {
      int rp = mybase + v[i];
      rowptr[idx] = rp;
      cursor[idx] = rp;
    }
  }
}

__global__ void k_scatter(const int* __restrict__ rows, const int* __restrict__ cols,
                          const float* __restrict__ vals, int nnz,
                          int* __restrict__ cursor, int2* __restrict__ epack) {
  int e = blockIdx.x * 256 + threadIdx.x;
  if (e >= nnz) return;
  int pos = atomicAdd(&cursor[rows[e]], 1);
  epack[pos] = make_int2(cols[e], __float_as_int(vals[e]));
}

// ---------------- fused gather SPMM (4 edges x float4 lanes per wave) ----------------

__global__ void k_spmm_prop(const int* __restrict__ rowptr, const int2* __restrict__ epack,
                            const float* __restrict__ xA, const float* __restrict__ xB,
                            int nA, const float* __restrict__ noise,
                            float* __restrict__ fout, float* __restrict__ outp,
                            int n, int write_f) {
  long long t = (long long)blockIdx.x * 256 + threadIdx.x;
  int row = (int)(t >> 6), lane = (int)(t & 63);
  if (row >= n) return;
  int q = lane >> 4, c = lane & 15;
  int s = rowptr[row], e = rowptr[row + 1];
  float4 a0 = {0.f, 0.f, 0.f, 0.f}, a1 = {0.f, 0.f, 0.f, 0.f};
  for (int kk = s; kk < e; kk += 8) {
    int i0 = kk + q, i1 = kk + 4 + q;
    int2 e0 = (i0 < e) ? epack[i0] : make_int2(0, 0);
    int2 e1 = (i1 < e) ? epack[i1] : make_int2(0, 0);
    const float* p0 = (e0.x < nA) ? (xA + (size_t)e0.x * DD)
                                  : (xB + (size_t)(e0.x - nA) * DD);
    const float* p1 = (e1.x < nA) ? (xA + (size_t)e1.x * DD)
                                  : (xB + (size_t)(e1.x - nA) * DD);
    float4 x0 = ((const float4*)p0)[c];
    float4 x1 = ((const float4*)p1)[c];
    float v0 = __int_as_float(e0.y), v1 = __int_as_float(e1.y);
    a0.x = fmaf(v0, x0.x, a0.x); a0.y = fmaf(v0, x0.y, a0.y);
    a0.z = fmaf(v0, x0.z, a0.z); a0.w = fmaf(v0, x0.w, a0.w);
    a1.x = fmaf(v1, x1.x, a1.x); a1.y = fmaf(v1, x1.y, a1.y);
    a1.z = fmaf(v1, x1.z, a1.z); a1.w = fmaf(v1, x1.w, a1.w);
  }
  float4 g;
  g.x = a0.x + a1.x; g.y = a0.y + a1.y; g.z = a0.z + a1.z; g.w = a0.w + a1.w;
  g.x += __shfl_xor(g.x, 16); g.y += __shfl_xor(g.y, 16);
  g.z += __shfl_xor(g.z, 16); g.w += __shfl_xor(g.w, 16);
  g.x += __shfl_xor(g.x, 32); g.y += __shfl_xor(g.y, 32);
  g.z += __shfl_xor(g.z, 32); g.w += __shfl_xor(g.w, 32);
  float4 nz = ((const float4*)(noise + (size_t)row * DD))[c];
  float nn = wave_sum(nz.x * nz.x + nz.y * nz.y + nz.z * nz.z + nz.w * nz.w) * 0.25f;
  float nf = 0.1f / fmaxf(sqrtf(nn), 1e-12f);
  float4 fv;
  fv.x = g.x + ((g.x > 0.f) ? 1.f : ((g.x < 0.f) ? -1.f : 0.f)) * nz.x * nf;
  fv.y = g.y + ((g.y > 0.f) ? 1.f : ((g.y < 0.f) ? -1.f : 0.f)) * nz.y * nf;
  fv.z = g.z + ((g.z > 0.f) ? 1.f : ((g.z < 0.f) ? -1.f : 0.f)) * nz.z * nf;
  fv.w = g.w + ((g.w > 0.f) ? 1.f : ((g.w < 0.f) ? -1.f : 0.f)) * nz.w * nf;
  float fn = wave_sum(fv.x * fv.x + fv.y * fv.y + fv.z * fv.z + fv.w * fv.w) * 0.25f;
  float inv = (1.f / 3.f) / fmaxf(sqrtf(fn), 1e-12f);
  if (lane < 16) {
    if (write_f) ((float4*)(fout + (size_t)row * DD))[c] = fv;
    float4 o = ((float4*)(outp + (size_t)row * DD))[c];
    o.x += fv.x * inv; o.y += fv.y * inv; o.z += fv.z * inv; o.w += fv.w * inv;
    ((float4*)(outp + (size_t)row * DD))[c] = o;
  }
}

__global__ void k_spmm_agg(const int* __restrict__ rowptr, const int2* __restrict__ epack,
                           const float* __restrict__ x, const float* __restrict__ noise,
                           float* __restrict__ out, int n) {
  long long t = (long long)blockIdx.x * 256 + threadIdx.x;
  int row = (int)(t >> 6), lane = (int)(t & 63);
  if (row >= n) return;
  int q = lane >> 4, c = lane & 15;
  int s = rowptr[row], e = rowptr[row + 1];
  float4 a0 = {0.f, 0.f, 0.f, 0.f}, a1 = {0.f, 0.f, 0.f, 0.f};
  for (int kk = s; kk < e; kk += 8) {
    int i0 = kk + q, i1 = kk + 4 + q;
    int2 e0 = (i0 < e) ? epack[i0] : make_int2(0, 0);
    int2 e1 = (i1 < e) ? epack[i1] : make_int2(0, 0);
    float4 x0 = ((const float4*)(x + (size_t)e0.x * DD))[c];
    float4 x1 = ((const float4*)(x + (size_t)e1.x * DD))[c];
    float v0 = __int_as_float(e0.y), v1 = __int_as_float(e1.y);
    a0.x = fmaf(v0, x0.x, a0.x); a0.y = fmaf(v0, x0.y, a0.y);
    a0.z = fmaf(v0, x0.z, a0.z); a0.w = fmaf(v0, x0.w, a0.w);
    a1.x = fmaf(v1, x1.x, a1.x); a1.y = fmaf(v1, x1.y, a1.y);
    a1.z = fmaf(v1, x1.z, a1.z); a1.w = fmaf(v1, x1.w, a1.w);
  }
  float4 g;
  g.x = a0.x + a1.x; g.y = a0.y + a1.y; g.z = a0.z + a1.z; g.w = a0.w + a1.w;
  g.x += __shfl_xor(g.x, 16); g.y += __shfl_xor(g.y, 16);
  g.z += __shfl_xor(g.z, 16); g.w += __shfl_xor(g.w, 16);
  g.x += __shfl_xor(g.x, 32); g.y += __shfl_xor(g.y, 32);
  g.z += __shfl_xor(g.z, 32); g.w += __shfl_xor(g.w, 32);
  float4 nz = ((const float4*)(noise + (size_t)row * DD))[c];
  float nn = wave_sum(nz.x * nz.x + nz.y * nz.y + nz.z * nz.z + nz.w * nz.w) * 0.25f;
  float nf = 0.1f / fmaxf(sqrtf(nn), 1e-12f);
  if (lane < 16) {
    float4 fv;
    fv.x = g.x + ((g.x > 0.f) ? 1.f : ((g.x < 0.f) ? -1.f : 0.f)) * nz.x * nf;
    fv.y = g.y + ((g.y > 0.f) ? 1.f : ((g.y < 0.f) ? -1.f : 0.f)) * nz.y * nf;
    fv.z = g.z + ((g.z > 0.f) ? 1.f : ((g.z < 0.f) ? -1.f : 0.f)) * nz.z * nf;
    fv.w = g.w + ((g.w > 0.f) ? 1.f : ((g.w < 0.f) ? -1.f : 0.f)) * nz.w * nf;
    ((float4*)(out + (size_t)row * DD))[c] = fv;
  }
}

// ---------------- heads ----------------

__global__ void k_bpr(const float* __restrict__ o_UI, const float* __restrict__ biu,
                      const float* __restrict__ uib, const float* __restrict__ o_BI,
                      const int* __restrict__ users, const int* __restrict__ bundles,
                      float* __restrict__ bpr_terms) {
  long long t = (long long)blockIdx.x * 256 + threadIdx.x;
  int w = (int)(t >> 6);
  int lane = (int)(t & 63);
  if (w >= BATCH) return;
  int u = users[w];
  int b0 = bundles[2 * w], b1 = bundles[2 * w + 1];
  float ur = 0.5f * (o_UI[(size_t)u * DD + lane] + biu[(size_t)u * DD + lane]);
  float br0 = 0.5f * (uib[(size_t)b0 * DD + lane] + o_BI[(size_t)b0 * DD + lane]);
  float br1 = 0.5f * (uib[(size_t)b1 * DD + lane] + o_BI[(size_t)b1 * DD + lane]);
  float pos = wave_sum(ur * br0);
  float neg = wave_sum(ur * br1);
  if (lane == 0) {
    float x = pos - neg;
    float loss = (x > 0.f) ? log1pf(expf(-x)) : (-x + log1pf(expf(x)));
    bpr_terms[w] = loss;
  }
}

__global__ void k_sumsq_p(const float* __restrict__ x, int n4, float* __restrict__ partials) {
  float s = 0.f;
  for (int i = blockIdx.x * 256 + threadIdx.x; i < n4; i += gridDim.x * 256) {
    float4 v = ((const float4*)x)[i];
    s += v.x * v.x + v.y * v.y + v.z * v.z + v.w * v.w;
  }
  s = wave_sum(s);
  __shared__ float part[4];
  if ((threadIdx.x & 63) == 0) part[threadIdx.x >> 6] = s;
  __syncthreads();
  if (threadIdx.x == 0) partials[blockIdx.x] = part[0] + part[1] + part[2] + part[3];
}

// build 6 normalized (2048 x 64) matrices, fp32 + bf16 copies
__global__ void k_gather(const float* __restrict__ o_UB, const float* __restrict__ o_UI,
                         const float* __restrict__ o_BI, const float* __restrict__ uib,
                         const float* __restrict__ biu, const int* __restrict__ users,
                         const int* __restrict__ bundles, float* __restrict__ P,
                         unsigned short* __restrict__ Pb) {
  long long t = (long long)blockIdx.x * 256 + threadIdx.x;
  int w = (int)(t >> 6);
  int lane = (int)(t & 63);
  if (w >= 6 * BATCH) return;
  int k = w / BATCH, b = w % BATCH;
  const float* src;
  if (k == 0)      src = o_UB + (size_t)users[b] * DD;
  else if (k == 1) src = o_UI + (size_t)users[b] * DD;
  else if (k == 2) src = biu + (size_t)users[b] * DD;
  else if (k == 3) src = o_UB + (size_t)(U_N + bundles[2 * b]) * DD;
  else if (k == 4) src = uib + (size_t)bundles[2 * b] * DD;
  else             src = o_BI + (size_t)bundles[2 * b] * DD;
  float v = src[lane];
  float n2 = wave_sum(v * v);
  float inv = 1.f / fmaxf(sqrtf(n2), 1e-12f);
  float pv = v * inv;
  P[(size_t)w * DD + lane] = pv;
  Pb[(size_t)w * DD + lane] = f2bf(pv);
}

// MFMA CL pair kernel: each wave computes a 64x256 S-chunk of one pair,
// ttl[p][i] += sum_j exp(4 * X_i . Y_j)   (atomic partial row-sums)
__global__ void k_clpair_mfma(const unsigned short* __restrict__ Pb,
                              float* __restrict__ ttl) {
  const int pairX[12] = {0, 0, 1, 0, 1, 2, 3, 3, 4, 3, 4, 5};
  const int pairY[12] = {1, 2, 2, 0, 1, 2, 4, 5, 5, 3, 4, 5};
  int wid = threadIdx.x >> 6;
  int lane = threadIdx.x & 63;
  int wtile = blockIdx.x * 4 + wid;     // 12 * 32 * 8 = 3072 wave-tiles
  int p = wtile >> 8;                   // / 256
  int rest = wtile & 255;
  int it = rest >> 3, jc = rest & 7;    // 64-row i-tile, 256-col j-chunk
  const unsigned short* X = Pb + (size_t)pairX[p] * BATCH * DD;
  const unsigned short* Y = Pb + (size_t)pairY[p] * BATCH * DD;
  int r = lane & 15, q = lane >> 4;
  // A-frags for the wave's 64 rows, both K-halves (A[m=lane&15][k=q*8+j])
  short8 A[2][4];
#pragma unroll
  for (int kh = 0; kh < 2; ++kh)
#pragma unroll
    for (int ii = 0; ii < 4; ++ii)
      A[kh][ii] = *(const short8*)(X + (size_t)(it * 64 + ii * 16 + r) * DD + kh * 32 + q * 8);
  float rs[4][4];  // [ii][reg] row-sums of exp
#pragma unroll
  for (int ii = 0; ii < 4; ++ii)
#pragma unroll
    for (int g = 0; g < 4; ++g) rs[ii][g] = 0.f;
  for (int jn = 0; jn < 4; ++jn) {
    int j0 = jc * 256 + jn * 64;
    floatx4 acc[4][4];
#pragma unroll
    for (int ii = 0; ii < 4; ++ii)
#pragma unroll
      for (int jj = 0; jj < 4; ++jj) acc[ii][jj] = (floatx4){0.f, 0.f, 0.f, 0.f};
#pragma unroll
    for (int kh = 0; kh < 2; ++kh) {
      short8 Bf[4];
#pragma unroll
      for (int jj = 0; jj < 4; ++jj)
        Bf[jj] = *(const short8*)(Y + (size_t)(j0 + jj * 16 + r) * DD + kh * 32 + q * 8);
#pragma unroll
      for (int ii = 0; ii < 4; ++ii)
#pragma unroll
        for (int jj = 0; jj < 4; ++jj)
          acc[ii][jj] = __builtin_amdgcn_mfma_f32_16x16x32_bf16(A[kh][ii], Bf[jj],
                                                                acc[ii][jj], 0, 0, 0);
    }
#pragma unroll
    for (int ii = 0; ii < 4; ++ii)
#pragma unroll
      for (int jj = 0; jj < 4; ++jj)
#pragma unroll
        for (int g = 0; g < 4; ++g) rs[ii][g] += __expf(4.0f * acc[ii][jj][g]);
  }
  // reduce over the 16 cols held across lanes sharing q (C/D: col=lane&15, row=q*4+reg)
#pragma unroll
  for (int off = 1; off < 16; off <<= 1)
#pragma unroll
    for (int ii = 0; ii < 4; ++ii)
#pragma unroll
      for (int g = 0; g < 4; ++g) rs[ii][g] += __shfl_xor(rs[ii][g], off);
  if (r == 0) {
#pragma unroll
    for (int ii = 0; ii < 4; ++ii)
#pragma unroll
      for (int g = 0; g < 4; ++g)
        unsafeAtomicAdd(&ttl[(size_t)p * BATCH + it * 64 + ii * 16 + q * 4 + g],
                        rs[ii][g]);
  }
}

// per (pair, i): ttl[p,i] <- log(ttl[p,i]) - diag/tau  (diag in fp32)
__global__ void k_cldiag(const float* __restrict__ P, float* __restrict__ ttl) {
  const int pairX[12] = {0, 0, 1, 0, 1, 2, 3, 3, 4, 3, 4, 5};
  const int pairY[12] = {1, 2, 2, 0, 1, 2, 4, 5, 5, 3, 4, 5};
  long long t = (long long)blockIdx.x * 256 + threadIdx.x;
  int w = (int)(t >> 6);
  int lane = (int)(t & 63);
  if (w >= 12 * BATCH) return;
  int p = w / BATCH, i = w % BATCH;
  float xv = P[((size_t)pairX[p] * BATCH + i) * DD + lane];
  float yv = P[((size_t)pairY[p] * BATCH + i) * DD + lane];
  float d = wave_sum(xv * yv);
  if (lane == 0) ttl[(size_t)p * BATCH + i] = logf(ttl[(size_t)p * BATCH + i]) - d * 4.0f;
}

__global__ void k_finalred(const float* __restrict__ bpr_terms,
                           const float* __restrict__ cl_terms,
                           const float* __restrict__ partials,
                           float* __restrict__ out) {
  int t = threadIdx.x;  // 1024
  float bpr = 0.f, reg = 0.f, inter = 0.f, intra = 0.f;
  for (int i = t; i < BATCH; i += 1024) bpr += bpr_terms[i];
  for (int i = t; i < 768; i += 1024) reg += partials[i];
  for (int i = t; i < 12 * BATCH; i += 1024) {
    int p = i >> 11;
    float v = cl_terms[i];
    if ((p % 6) < 3) inter += v; else intra += v;
  }
  bpr = wave_sum(bpr); reg = wave_sum(reg);
  inter = wave_sum(inter); intra = wave_sum(intra);
  __shared__ float sb[16], sr[16], si[16], sx[16];
  int w = t >> 6, lane = t & 63;
  if (lane == 0) { sb[w] = bpr; sr[w] = reg; si[w] = inter; sx[w] = intra; }
  __syncthreads();
  if (t == 0) {
    float Bs = 0, Rs = 0, Is = 0, Xs = 0;
    for (int i = 0; i < 16; ++i) { Bs += sb[i]; Rs += sr[i]; Is += si[i]; Xs += sx[i]; }
    out[0] = Bs / (float)BATCH + 1e-5f * Rs;
    out[1] = 0.04f * (0.5f * Is + 0.5f * Xs) / (float)BATCH;
  }
}

}  // namespace

extern "C" void kernel_launch(void* const* d_in, const int* in_sizes, int n_in,
                              void* d_out, int out_size, void* d_ws, size_t ws_size,
                              hipStream_t stream) {
  const float* usersF = (const float*)d_in[0];
  const float* bundlesF = (const float*)d_in[1];
  const float* itemsF = (const float*)d_in[2];
  const int* ub_rows = (const int*)d_in[3];
  const int* ub_cols = (const int*)d_in[4];
  const float* ub_vals = (const float*)d_in[5];
  const int* ui_rows = (const int*)d_in[6];
  const int* ui_cols = (const int*)d_in[7];
  const float* ui_vals = (const float*)d_in[8];
  const int* bi_rows = (const int*)d_in[9];
  const int* bi_cols = (const int*)d_in[10];
  const float* bi_vals = (const float*)d_in[11];
  const int* biagg_rows = (const int*)d_in[12];
  const int* biagg_cols = (const int*)d_in[13];
  const float* biagg_vals = (const float*)d_in[14];
  const int* uiagg_rows = (const int*)d_in[15];
  const int* uiagg_cols = (const int*)d_in[16];
  const float* uiagg_vals = (const float*)d_in[17];
  const float* noise_UB = (const float*)d_in[18];
  const float* noise_UI = (const float*)d_in[19];
  const float* noise_BI = (const float*)d_in[20];
  const float* noise_agg_BI = (const float*)d_in[21];
  const float* noise_agg_UI = (const float*)d_in[22];
  const int* users = (const int*)d_in[23];
  const int* bundles = (const int*)d_in[24];
  int nnz_ub = in_sizes[3], nnz_ui = in_sizes[6], nnz_bi = in_sizes[9];
  int nnz_biagg = in_sizes[12], nnz_uiagg = in_sizes[15];

  float* ws = (float*)d_ws;
  size_t off = 0;
  float* o_UB = ws + off; off += (size_t)(U_N + B_N) * DD;
  float* o_UI = ws + off; off += (size_t)(U_N + I_N) * DD;
  float* o_BI = ws + off; off += (size_t)(B_N + I_N) * DD;
  float* uib  = ws + off; off += (size_t)B_N * DD;
  float* biu  = ws + off; off += (size_t)U_N * DD;
  float* s2   = ws + off; off += (size_t)(U_N + I_N) * DD;
  float* P    = ws + off; off += (size_t)6 * BATCH * DD;
  float* ttl  = ws + off; off += (size_t)12 * BATCH;
  float* bprT = ws + off; off += BATCH;
  float* prt  = ws + off; off += 768;
  // Pb (bf16 copy of P) aliases s2: s2 is dead after the last spmm_prop
  unsigned short* Pb = (unsigned short*)s2;
  constexpr int N1 = 340000, N2 = 70000;
  int* cnt  = (int*)(ws + off); off += N1;        // also scatter cursor (aliased)
  int* rptr = (int*)(ws + off); off += N1 + 1;
  int* bsum = (int*)(ws + off); off += 256;
  int* boff = (int*)(ws + off); off += 256;
  off = (off + 1) & ~(size_t)1;  // 8B align
  int2* epack = (int2*)(ws + off); off += (size_t)5200000 * 2;
  if (ws_size < off * sizeof(float)) return;  // insufficient workspace

  auto scan_phase = [&](int n_total) {
    int nb = (n_total + SCAN_ELEMS - 1) / SCAN_ELEMS;  // <= 167 <= 256
    k_psum<<<nb, 256, 0, stream>>>(cnt, n_total, bsum);
    k_bscan<<<1, 256, 0, stream>>>(bsum, nb, boff, rptr + n_total);
    k_apply<<<nb, 256, 0, stream>>>(cnt, n_total, boff, rptr, cnt);
  };

  // ---- phase-1 CSR: UB rows [0,70000), UI rows [70000,220000), BI rows [220000,340000)
  int* cnt_ub = cnt,        * cnt_ui = cnt + 70000,  * cnt_bi = cnt + 220000;
  int* rp_ub  = rptr,       * rp_ui  = rptr + 70000, * rp_bi  = rptr + 220000;
  hipMemsetAsync(cnt, 0, (size_t)N1 * sizeof(int), stream);
  k_hist<<<(nnz_ub + 255) / 256, 256, 0, stream>>>(ub_rows, nnz_ub, cnt_ub);
  k_hist<<<(nnz_ui + 255) / 256, 256, 0, stream>>>(ui_rows, nnz_ui, cnt_ui);
  k_hist<<<(nnz_bi + 255) / 256, 256, 0, stream>>>(bi_rows, nnz_bi, cnt_bi);
  scan_phase(N1);
  k_scatter<<<(nnz_ub + 255) / 256, 256, 0, stream>>>(ub_rows, ub_cols, ub_vals, nnz_ub, cnt_ub, epack);
  k_scatter<<<(nnz_ui + 255) / 256, 256, 0, stream>>>(ui_rows, ui_cols, ui_vals, nnz_ui, cnt_ui, epack);
  k_scatter<<<(nnz_bi + 255) / 256, 256, 0, stream>>>(bi_rows, bi_cols, bi_vals, nnz_bi, cnt_bi, epack);

  auto propagate = [&](const float* A, const float* Bf, int nA, int nB,
                       const int* rp, const float* noise, float* outp) {
    int n = nA + nB;
    int tot4 = n * (DD / 4);
    k_init0<<<(tot4 + 255) / 256, 256, 0, stream>>>(A, Bf, outp, nA, n);
    int gp = (int)(((long long)n * 64 + 255) / 256);
    k_spmm_prop<<<gp, 256, 0, stream>>>(rp, epack, A, Bf, nA, noise, s2, outp, n, 1);
    k_spmm_prop<<<gp, 256, 0, stream>>>(rp, epack, s2, s2, n, noise + (size_t)n * DD,
                                        nullptr, outp, n, 0);
  };

  propagate(usersF, bundlesF, U_N, B_N, rp_ub, noise_UB, o_UB);
  propagate(usersF, itemsF, U_N, I_N, rp_ui, noise_UI, o_UI);
  propagate(bundlesF, itemsF, B_N, I_N, rp_bi, noise_BI, o_BI);

  // ---- phase-2 CSR: BIAGG rows [0,20000), UIAGG rows [20000,70000)
  int* cnt_ba = cnt,  * cnt_ua = cnt + 20000;
  int* rp_ba  = rptr, * rp_ua  = rptr + 20000;
  hipMemsetAsync(cnt, 0, (size_t)N2 * sizeof(int), stream);
  k_hist<<<(nnz_biagg + 255) / 256, 256, 0, stream>>>(biagg_rows, nnz_biagg, cnt_ba);
  k_hist<<<(nnz_uiagg + 255) / 256, 256, 0, stream>>>(uiagg_rows, nnz_uiagg, cnt_ua);
  scan_phase(N2);
  k_scatter<<<(nnz_biagg + 255) / 256, 256, 0, stream>>>(biagg_rows, biagg_cols, biagg_vals,
                                                         nnz_biagg, cnt_ba, epack);
  k_scatter<<<(nnz_uiagg + 255) / 256, 256, 0, stream>>>(uiagg_rows, uiagg_cols, uiagg_vals,
                                                         nnz_uiagg, cnt_ua, epack);
  k_spmm_agg<<<(int)(((long long)B_N * 64 + 255) / 256), 256, 0, stream>>>(
      rp_ba, epack, o_UI + (size_t)U_N * DD, noise_agg_BI, uib, B_N);
  k_spmm_agg<<<(int)(((long long)U_N * 64 + 255) / 256), 256, 0, stream>>>(
      rp_ua, epack, o_BI + (size_t)B_N * DD, noise_agg_UI, biu, U_N);

  // heads
  k_bpr<<<BATCH * 64 / 256, 256, 0, stream>>>(o_UI, biu, uib, o_BI, users, bundles, bprT);
  k_sumsq_p<<<256, 256, 0, stream>>>(usersF, U_N * DD / 4, prt);
  k_sumsq_p<<<256, 256, 0, stream>>>(bundlesF, B_N * DD / 4, prt + 256);
  k_sumsq_p<<<256, 256, 0, stream>>>(itemsF, I_N * DD / 4, prt + 512);
  k_gather<<<6 * BATCH * 64 / 256, 256, 0, stream>>>(o_UB, o_UI, o_BI, uib, biu,
                                                     users, bundles, P, Pb);
  hipMemsetAsync(ttl, 0, (size_t)12 * BATCH * sizeof(float), stream);
  k_clpair_mfma<<<768, 256, 0, stream>>>(Pb, ttl);
  k_cldiag<<<12 * BATCH * 64 / 256, 256, 0, stream>>>(P, ttl);
  k_finalred<<<1, 1024, 0, stream>>>(bprT, ttl, prt, (float*)d_out);
}